// Round 2
// baseline (15556.757 us; speedup 1.0000x reference)
//
#include <hip/hip_runtime.h>
#include <hip/hip_bf16.h>

typedef __hip_bfloat16 bf16;
typedef unsigned int uint_t;
typedef unsigned short ushort_t;

constexpr int NB  = 64;    // batch
constexpr int NL  = 64;    // words per sentence
constexpr int NT  = 63;    // template steps
constexpr int NCL = 16;    // chars per word
constexpr int NS  = 128;   // 1 + NL + NT
constexpr int ND  = 300;   // embed dim / hidden U
constexpr int NU  = 300;
constexpr int NCE = 8;
constexpr int NCF = 100;
constexpr int NCW = 5;
constexpr int NDIN = 400;  // ND + NCF
constexpr int NH4 = 1200;
constexpr int NH8 = 2400;
constexpr int NCLS = 3;

__device__ __forceinline__ float sigf(float x)  { return 1.0f/(1.0f + __expf(-x)); }
__device__ __forceinline__ float tanhf_(float x){ return 2.0f/(1.0f + __expf(-2.0f*x)) - 1.0f; }
__device__ __forceinline__ ushort_t f2bf(float f){ bf16 v = __float2bfloat16(f); return *(ushort_t*)&v; }

// ---------------- embedding + char CNN -> tree leaf rows ----------------
__global__ void k_embed(const int* __restrict__ x, const int* __restrict__ chars,
                        const float* __restrict__ wemb, const float* __restrict__ cemb,
                        const float* __restrict__ filt, float* __restrict__ tout)
{
    int bl = blockIdx.x;
    int b = bl / NL, l = bl - b*NL;
    __shared__ float e[NCL][NCE];
    __shared__ int wid;
    int tid = threadIdx.x;
    if (tid < NCL*NCE) {
        int ci = tid / NCE, cc = tid - (tid/NCE)*NCE;
        int ch = chars[bl*NCL + ci];
        e[ci][cc] = cemb[ch*NCE + cc];
    }
    if (tid == 0) wid = x[bl];
    __syncthreads();
    float* dst = tout + ((size_t)b*NS + 1 + l) * NDIN;
    if (tid < NCF) {
        float mx = -1e30f;
        for (int w = 0; w < NCL-NCW+1; ++w) {
            float acc = 0.f;
            #pragma unroll
            for (int k = 0; k < NCW; ++k)
                #pragma unroll
                for (int c = 0; c < NCE; ++c)
                    acc += e[w+k][c] * filt[(k*NCE+c)*NCF + tid];
            mx = fmaxf(mx, acc);
        }
        dst[ND + tid] = mx;
    }
    int w0 = wid;
    for (int i = tid; i < ND; i += blockDim.x)
        dst[i] = wemb[(size_t)w0*ND + i];
}

// ---------------- tree unfold ----------------
__global__ void k_tree(const int* __restrict__ temp, const int* __restrict__ len_,
                       float* __restrict__ tr)
{
    int half = blockIdx.x, b = blockIdx.y;
    int d0base = half*200;
    __shared__ float lds[65*200];
    int tid = threadIdx.x;
    float* base = tr + (size_t)b*NS*NDIN;
    for (int i = tid; i < 65*200; i += 256) {
        int r = i/200, d = i - r*200;
        lds[i] = base[r*NDIN + d0base + d];
    }
    __syncthreads();
    int ln = len_[b];
    for (int s = 1; s < NT; ++s) {
        int c0 = temp[(b*NT + s)*2 + 0];
        int c1 = temp[(b*NT + s)*2 + 1];
        int tgt = ln + 1 + s;
        if (tid < 200) {
            int d = tid;
            float p = 0.5f*(lds[c0*200 + d] + lds[c1*200 + d]);
            if (tgt <= NL) lds[tgt*200 + d] += p;
            else base[(size_t)tgt*NDIN + d0base + d] = p;
        }
    }
    __syncthreads();
    for (int i = tid; i < 65*200; i += 256) {
        int r = i/200, d = i - r*200;
        base[r*NDIN + d0base + d] = lds[i];
    }
}

// ---------------- generic transpose out[c][r] = in[r][c] ----------------
__global__ void k_transp(const float* __restrict__ in, float* __restrict__ out, int R, int C)
{
    __shared__ float tile[32][33];
    int c0 = blockIdx.x*32, r0 = blockIdx.y*32;
    for (int i = threadIdx.y; i < 32; i += 8) {
        int r = r0 + i, c = c0 + threadIdx.x;
        tile[i][threadIdx.x] = (r < R && c < C) ? in[(size_t)r*C + c] : 0.f;
    }
    __syncthreads();
    for (int i = threadIdx.y; i < 32; i += 8) {
        int c = c0 + i, r = r0 + threadIdx.x;
        if (c < C && r < R) out[(size_t)c*R + r] = tile[threadIdx.x][i];
    }
}

// ---------------- generic tiled GEMM  C = A@B (+bias)(relu) ----------------
template<int APERM, int OMODE, int ACT>
__global__ void k_gemm_nn(const float* __restrict__ A, const float* __restrict__ Bm,
                          const float* __restrict__ bias, void* __restrict__ Cv,
                          int M, int N, int K,
                          long long strideA, long long strideB, long long strideC)
{
    int bz = blockIdx.z;
    const float* Ab = A + (size_t)bz*strideA;
    const float* Bb = Bm + (size_t)bz*strideB;
    __shared__ float As[16][64];
    __shared__ float Bs[16][68];
    int n0 = blockIdx.x*64, m0 = blockIdx.y*64;
    int tid = threadIdx.x;
    int tm = tid/16, tn = tid - tm*16;
    float acc[4][4] = {};
    for (int k0 = 0; k0 < K; k0 += 16) {
        {
            int row = tid>>2, kq = tid&3;
            int m = m0 + row;
            int arow;
            if (APERM) { int tq = m>>6, bb = m&63; arow = bb*NS + tq; } else arow = m;
            const float* src = Ab + (size_t)arow*K + k0 + kq*4;
            float4 v;
            if (k0 + 16 <= K) v = *(const float4*)src;
            else {
                v.x = (k0+kq*4+0 < K)? src[0] : 0.f;
                v.y = (k0+kq*4+1 < K)? src[1] : 0.f;
                v.z = (k0+kq*4+2 < K)? src[2] : 0.f;
                v.w = (k0+kq*4+3 < K)? src[3] : 0.f;
            }
            As[kq*4+0][row]=v.x; As[kq*4+1][row]=v.y; As[kq*4+2][row]=v.z; As[kq*4+3][row]=v.w;
        }
        {
            int kk = tid>>4, nq = tid&15;
            int n = n0 + nq*4; int kg = k0 + kk;
            float4 v = {0,0,0,0};
            if (kg < K) {
                const float* src = Bb + (size_t)kg*N + n;
                if (n + 4 <= N) v = *(const float4*)src;
                else { if(n+0<N)v.x=src[0]; if(n+1<N)v.y=src[1]; if(n+2<N)v.z=src[2]; }
            }
            Bs[kk][nq*4+0]=v.x; Bs[kk][nq*4+1]=v.y; Bs[kk][nq*4+2]=v.z; Bs[kk][nq*4+3]=v.w;
        }
        __syncthreads();
        #pragma unroll
        for (int kk = 0; kk < 16; ++kk) {
            float4 a  = *(const float4*)&As[kk][tm*4];
            float4 bq = *(const float4*)&Bs[kk][tn*4];
            acc[0][0]+=a.x*bq.x; acc[0][1]+=a.x*bq.y; acc[0][2]+=a.x*bq.z; acc[0][3]+=a.x*bq.w;
            acc[1][0]+=a.y*bq.x; acc[1][1]+=a.y*bq.y; acc[1][2]+=a.y*bq.z; acc[1][3]+=a.y*bq.w;
            acc[2][0]+=a.z*bq.x; acc[2][1]+=a.z*bq.y; acc[2][2]+=a.z*bq.z; acc[2][3]+=a.z*bq.w;
            acc[3][0]+=a.w*bq.x; acc[3][1]+=a.w*bq.y; acc[3][2]+=a.w*bq.z; acc[3][3]+=a.w*bq.w;
        }
        __syncthreads();
    }
    #pragma unroll
    for (int i = 0; i < 4; ++i) {
        int m = m0 + tm*4 + i;
        #pragma unroll
        for (int j = 0; j < 4; ++j) {
            int n = n0 + tn*4 + j;
            if (n >= N) continue;
            float val = acc[i][j];
            if (bias) val += bias[n];
            if (ACT == 1) val = fmaxf(val, 0.f);
            if (OMODE == 0) {
                float* C = (float*)Cv + (size_t)bz*strideC;
                C[(size_t)m*N + n] = val;
            } else {
                int tq = m>>6, bb = m&63;
                ((bf16*)Cv)[((size_t)tq*NH4 + n)*NB + bb] = __float2bfloat16(val);
            }
        }
    }
}

// ---------------- batched sim = h1 @ h2^T ----------------
__global__ void k_gemm_nt_sim(const float* __restrict__ h1g, const float* __restrict__ h2g,
                              float* __restrict__ sim, float* __restrict__ simT)
{
    int bz = blockIdx.z;
    const float* Ab = h1g + (size_t)bz*NS*(2*NU);
    const float* Bb = h2g + (size_t)bz*NS*(2*NU);
    __shared__ float As[16][64];
    __shared__ float Bs[16][68];
    int n0 = blockIdx.x*64, m0 = blockIdx.y*64;
    int tid = threadIdx.x;
    int tm = tid/16, tn = tid - tm*16;
    float acc[4][4] = {};
    const int K = 2*NU;
    for (int k0 = 0; k0 < K; k0 += 16) {
        int row = tid>>2, kq = tid&3;
        bool full = (k0 + 16 <= K);
        {
            const float* src = Ab + (size_t)(m0+row)*K + k0 + kq*4;
            float4 v = {0,0,0,0};
            if (full) v = *(const float4*)src;
            else { if(k0+kq*4+0<K)v.x=src[0]; if(k0+kq*4+1<K)v.y=src[1];
                   if(k0+kq*4+2<K)v.z=src[2]; if(k0+kq*4+3<K)v.w=src[3]; }
            As[kq*4+0][row]=v.x; As[kq*4+1][row]=v.y; As[kq*4+2][row]=v.z; As[kq*4+3][row]=v.w;
        }
        {
            const float* src = Bb + (size_t)(n0+row)*K + k0 + kq*4;
            float4 v = {0,0,0,0};
            if (full) v = *(const float4*)src;
            else { if(k0+kq*4+0<K)v.x=src[0]; if(k0+kq*4+1<K)v.y=src[1];
                   if(k0+kq*4+2<K)v.z=src[2]; if(k0+kq*4+3<K)v.w=src[3]; }
            Bs[kq*4+0][row]=v.x; Bs[kq*4+1][row]=v.y; Bs[kq*4+2][row]=v.z; Bs[kq*4+3][row]=v.w;
        }
        __syncthreads();
        #pragma unroll
        for (int kk = 0; kk < 16; ++kk) {
            float4 a  = *(const float4*)&As[kk][tm*4];
            float4 bq = *(const float4*)&Bs[kk][tn*4];
            acc[0][0]+=a.x*bq.x; acc[0][1]+=a.x*bq.y; acc[0][2]+=a.x*bq.z; acc[0][3]+=a.x*bq.w;
            acc[1][0]+=a.y*bq.x; acc[1][1]+=a.y*bq.y; acc[1][2]+=a.y*bq.z; acc[1][3]+=a.y*bq.w;
            acc[2][0]+=a.z*bq.x; acc[2][1]+=a.z*bq.y; acc[2][2]+=a.z*bq.z; acc[2][3]+=a.z*bq.w;
            acc[3][0]+=a.w*bq.x; acc[3][1]+=a.w*bq.y; acc[3][2]+=a.w*bq.z; acc[3][3]+=a.w*bq.w;
        }
        __syncthreads();
    }
    #pragma unroll
    for (int i = 0; i < 4; ++i) {
        int m = m0 + tm*4 + i;
        #pragma unroll
        for (int j = 0; j < 4; ++j) {
            int n = n0 + tn*4 + j;
            float val = acc[i][j];
            sim [((size_t)bz*NS + m)*NS + n] = val;
            simT[((size_t)bz*NS + n)*NS + m] = val;
        }
    }
}

// ---------------- row softmax (rows of length NS=128) ----------------
__global__ void k_softmax(const float* __restrict__ in, float* __restrict__ out)
{
    int r = blockIdx.x, tid = threadIdx.x;
    float v = in[(size_t)r*NS + tid];
    float m = v;
    for (int o = 32; o > 0; o >>= 1) m = fmaxf(m, __shfl_down(m, o, 64));
    __shared__ float red[2];
    if ((tid & 63) == 0) red[tid>>6] = m;
    __syncthreads();
    m = fmaxf(red[0], red[1]);
    float e = __expf(v - m);
    float s = e;
    for (int o = 32; o > 0; o >>= 1) s += __shfl_down(s, o, 64);
    __shared__ float red2[2];
    if ((tid & 63) == 0) red2[tid>>6] = s;
    __syncthreads();
    s = red2[0] + red2[1];
    out[(size_t)r*NS + tid] = e / s;
}

// ---------------- p = relu([h, a, h*a, h-a] @ dec_W + dec_b) ----------------
__global__ void k_m_gemm(const float* __restrict__ Hp, const float* __restrict__ Ap,
                         const float* __restrict__ Wd, const float* __restrict__ bd,
                         float* __restrict__ P)
{
    __shared__ float As[16][64];
    __shared__ float Bs[16][68];
    const int N = ND, K = NH8;
    int n0 = blockIdx.x*64, m0 = blockIdx.y*64;
    int tid = threadIdx.x;
    int tm = tid/16, tn = tid - tm*16;
    float acc[4][4] = {};
    for (int k0 = 0; k0 < K; k0 += 16) {
        {
            int row = tid>>2, kq = tid&3;
            int m = m0 + row;
            const float* hrow = Hp + (size_t)m*(2*NU);
            const float* arow = Ap + (size_t)m*(2*NU);
            #pragma unroll
            for (int jj = 0; jj < 4; ++jj) {
                int k = k0 + kq*4 + jj;
                int sel = k / 600, kk2 = k - sel*600;
                float hv = hrow[kk2], av = arow[kk2];
                float val = (sel==0)? hv : (sel==1)? av : (sel==2)? hv*av : hv - av;
                As[kq*4+jj][row] = val;
            }
        }
        {
            int kk = tid>>4, nq = tid&15;
            int n = n0 + nq*4; int kg = k0 + kk;
            const float* src = Wd + (size_t)kg*N + n;
            float4 v = {0,0,0,0};
            if (n + 4 <= N) v = *(const float4*)src;
            else { if(n+0<N)v.x=src[0]; if(n+1<N)v.y=src[1]; if(n+2<N)v.z=src[2]; }
            Bs[kk][nq*4+0]=v.x; Bs[kk][nq*4+1]=v.y; Bs[kk][nq*4+2]=v.z; Bs[kk][nq*4+3]=v.w;
        }
        __syncthreads();
        #pragma unroll
        for (int kk = 0; kk < 16; ++kk) {
            float4 a  = *(const float4*)&As[kk][tm*4];
            float4 bq = *(const float4*)&Bs[kk][tn*4];
            acc[0][0]+=a.x*bq.x; acc[0][1]+=a.x*bq.y; acc[0][2]+=a.x*bq.z; acc[0][3]+=a.x*bq.w;
            acc[1][0]+=a.y*bq.x; acc[1][1]+=a.y*bq.y; acc[1][2]+=a.y*bq.z; acc[1][3]+=a.y*bq.w;
            acc[2][0]+=a.z*bq.x; acc[2][1]+=a.z*bq.y; acc[2][2]+=a.z*bq.z; acc[2][3]+=a.z*bq.w;
            acc[3][0]+=a.w*bq.x; acc[3][1]+=a.w*bq.y; acc[3][2]+=a.w*bq.z; acc[3][3]+=a.w*bq.w;
        }
        __syncthreads();
    }
    #pragma unroll
    for (int i = 0; i < 4; ++i) {
        int m = m0 + tm*4 + i;
        #pragma unroll
        for (int j = 0; j < 4; ++j) {
            int n = n0 + tn*4 + j;
            if (n >= N) continue;
            P[(size_t)m*N + n] = fmaxf(acc[i][j] + bd[n], 0.f);
        }
    }
}

// ---------------- persistent bidirectional LSTM phase (all 128 steps, 1 launch) ---------
// grid 300 = 4 scans x 75 unit-blocks; block 128 = 4 units x 32 batch-pairs.
// LDS: weights (4u x 4g x 300) fp32 loaded ONCE + h (300 x 64) bf16 staged per step.
// 57.6 KB LDS -> 2 blocks/CU -> 300 blocks guaranteed co-resident (capacity 512).
// Grid barrier: release fence -> atomic arrive -> agent-scope poll -> acquire fence.
__global__ __launch_bounds__(128) void k_lstm_phase(
    const bf16* __restrict__ pre0, const bf16* __restrict__ pre1,
    const bf16* __restrict__ pre2, const bf16* __restrict__ pre3,
    const float* __restrict__ WTf, const float* __restrict__ WTb,
    float* __restrict__ hT1, float* __restrict__ hT2,
    ushort_t* __restrict__ hping,      // [2][4][300][64] bf16 ping-pong
    int* __restrict__ barcnt)
{
    __shared__ float   ws[16*300];     // [u_local*4+g][k]
    __shared__ ushort_t hs[300*64];    // h_{t-1} bf16 [k][b]
    int blk = blockIdx.x;
    int scan = blk / 75, cb = blk - scan*75;
    int u0 = cb*4;
    int tid = threadIdx.x;
    const bf16* pre = (scan==0)?pre0:(scan==1)?pre1:(scan==2)?pre2:pre3;
    const float* WT = (scan & 1)? WTb : WTf;
    float* hT = (scan < 2)? hT1 : hT2;
    int coff = (scan & 1)? NU : 0;
    int ul = tid >> 5, bp = tid & 31, b0 = bp*2;
    int u = u0 + ul;
    const int G = 300;

    // stage weights once (vectorized): 16 rows x 300
    for (int i = tid; i < 16*75; i += 128) {
        int r = i / 75, q = i - r*75;
        int urow = r >> 2, g = r & 3;
        float4 v = *(const float4*)&WT[(size_t)(g*NU + u0 + urow)*NU + q*4];
        *(float4*)&ws[r*300 + q*4] = v;
    }

    float creg[2] = {0.f, 0.f};
    for (int t = 0; t < NS; ++t) {
        float accg[4][2] = {{0,0},{0,0},{0,0},{0,0}};
        if (t > 0) {
            // ---- grid barrier #t ----
            __threadfence();                     // release: drain my h stores
            __syncthreads();
            if (tid == 0) {
                atomicAdd(barcnt, 1);
                while (__hip_atomic_load(barcnt, __ATOMIC_RELAXED, __HIP_MEMORY_SCOPE_AGENT) < t*G)
                    __builtin_amdgcn_s_sleep(2);
            }
            __syncthreads();
            __threadfence();                     // acquire: invalidate stale L1/L2
            // ---- stage h_{t-1} (bf16, vectorized 16B) ----
            const uint4* src = (const uint4*)(hping + ((size_t)((t+1)&1)*4 + scan)*NU*NB);
            uint4* dst = (uint4*)hs;
            for (int i = tid; i < NU*NB/8; i += 128) dst[i] = src[i];
            __syncthreads();
            // ---- hh matmul: 4 gates x 2 batches, K=300 ----
            const float* wp = ws + ul*4*300;
            for (int j = 0; j < 300; j += 4) {
                float4 w0 = *(const float4*)(wp + 0*300 + j);
                float4 w1 = *(const float4*)(wp + 1*300 + j);
                float4 w2 = *(const float4*)(wp + 2*300 + j);
                float4 w3 = *(const float4*)(wp + 3*300 + j);
                uint_t hv0 = *(const uint_t*)&hs[(j+0)*NB + b0];
                uint_t hv1 = *(const uint_t*)&hs[(j+1)*NB + b0];
                uint_t hv2 = *(const uint_t*)&hs[(j+2)*NB + b0];
                uint_t hv3 = *(const uint_t*)&hs[(j+3)*NB + b0];
                float x0l = __uint_as_float(hv0 << 16), x0h = __uint_as_float(hv0 & 0xffff0000u);
                float x1l = __uint_as_float(hv1 << 16), x1h = __uint_as_float(hv1 & 0xffff0000u);
                float x2l = __uint_as_float(hv2 << 16), x2h = __uint_as_float(hv2 & 0xffff0000u);
                float x3l = __uint_as_float(hv3 << 16), x3h = __uint_as_float(hv3 & 0xffff0000u);
                accg[0][0] += w0.x*x0l + w0.y*x1l + w0.z*x2l + w0.w*x3l;
                accg[0][1] += w0.x*x0h + w0.y*x1h + w0.z*x2h + w0.w*x3h;
                accg[1][0] += w1.x*x0l + w1.y*x1l + w1.z*x2l + w1.w*x3l;
                accg[1][1] += w1.x*x0h + w1.y*x1h + w1.z*x2h + w1.w*x3h;
                accg[2][0] += w2.x*x0l + w2.y*x1l + w2.z*x2l + w2.w*x3l;
                accg[2][1] += w2.x*x0h + w2.y*x1h + w2.z*x2h + w2.w*x3h;
                accg[3][0] += w3.x*x0l + w3.y*x1l + w3.z*x2l + w3.w*x3l;
                accg[3][1] += w3.x*x0h + w3.y*x1h + w3.z*x2h + w3.w*x3h;
            }
        }
        int tt = (scan & 1)? (NS-1-t) : t;
        const bf16* pp = pre + (size_t)tt*NH4*NB;
        ushort_t* hw = hping + ((size_t)(t&1)*4 + scan)*NU*NB + u*NB;
        ushort_t hbits[2];
        #pragma unroll
        for (int bb = 0; bb < 2; ++bb) {
            int b = b0 + bb;
            float iv = accg[0][bb] + __bfloat162float(pp[(0*NU+u)*NB + b]);
            float gv = accg[1][bb] + __bfloat162float(pp[(1*NU+u)*NB + b]);
            float fv = accg[2][bb] + __bfloat162float(pp[(2*NU+u)*NB + b]);
            float ov = accg[3][bb] + __bfloat162float(pp[(3*NU+u)*NB + b]);
            float c = sigf(fv + 1.0f)*creg[bb] + sigf(iv)*tanhf_(gv);
            float h = sigf(ov)*tanhf_(c);
            creg[bb] = c;
            hbits[bb] = f2bf(h);
            hT[((size_t)tt*(2*NU) + coff + u)*NB + b] = h;
        }
        *(uint_t*)&hw[b0] = (uint_t)hbits[0] | ((uint_t)hbits[1] << 16);
    }
}

// ---------------- pool: sum & max over t from hT layout (NS,600,NB) ----------------
__global__ void k_pool(const float* __restrict__ dT, float* __restrict__ v, int voff)
{
    int u = blockIdx.x*4 + (threadIdx.x >> 6);
    int b = threadIdx.x & 63;
    float s = 0.f, m = -1e30f;
    for (int t = 0; t < NS; ++t) {
        float x = dT[((size_t)t*(2*NU) + u)*NB + b];
        s += x; m = fmaxf(m, x);
    }
    v[(size_t)b*NH8 + voff + u]       = s;
    v[(size_t)b*NH8 + voff + 600 + u] = m;
}

// ---------------- final MLP ----------------
__global__ void k_final(const float* __restrict__ v, const float* __restrict__ W1,
                        const float* __restrict__ b1, const float* __restrict__ W2,
                        const float* __restrict__ b2, float* __restrict__ out)
{
    __shared__ float vl[NH8];
    __shared__ float yl[ND];
    int b = blockIdx.x, tid = threadIdx.x;
    for (int i = tid; i < NH8; i += 320) vl[i] = v[(size_t)b*NH8 + i];
    __syncthreads();
    if (tid < ND) {
        float acc = b1[tid];
        for (int k = 0; k < NH8; ++k) acc += vl[k]*W1[(size_t)k*ND + tid];
        yl[tid] = tanhf_(acc);
    }
    __syncthreads();
    if (tid < NCLS) {
        float acc = b2[tid];
        for (int u = 0; u < ND; ++u) acc += yl[u]*W2[u*NCLS + tid];
        out[b*NCLS + tid] = acc;
    }
}

extern "C" void kernel_launch(void* const* d_in, const int* in_sizes, int n_in,
                              void* d_out, int out_size, void* d_ws, size_t ws_size,
                              hipStream_t stream)
{
    const int*   x1     = (const int*)d_in[0];
    const int*   x2     = (const int*)d_in[1];
    const int*   char1  = (const int*)d_in[2];
    const int*   char2  = (const int*)d_in[3];
    const int*   temp1  = (const int*)d_in[6];
    const int*   temp2  = (const int*)d_in[7];
    const int*   len1   = (const int*)d_in[8];
    const int*   len2   = (const int*)d_in[9];
    const float* wemb   = (const float*)d_in[10];
    const float* cemb   = (const float*)d_in[11];
    const float* cfilt  = (const float*)d_in[12];
    const float* eWxf   = (const float*)d_in[13];
    const float* eWhf   = (const float*)d_in[14];
    const float* ebf    = (const float*)d_in[15];
    const float* eWxb   = (const float*)d_in[16];
    const float* eWhb   = (const float*)d_in[17];
    const float* ebb    = (const float*)d_in[18];
    const float* decW   = (const float*)d_in[19];
    const float* decb   = (const float*)d_in[20];
    const float* dWxf   = (const float*)d_in[21];
    const float* dWhf   = (const float*)d_in[22];
    const float* dbf    = (const float*)d_in[23];
    const float* dWxb   = (const float*)d_in[24];
    const float* dWhb   = (const float*)d_in[25];
    const float* dbb    = (const float*)d_in[26];
    const float* aW1    = (const float*)d_in[27];
    const float* ab1    = (const float*)d_in[28];
    const float* aW2    = (const float*)d_in[29];
    const float* ab2    = (const float*)d_in[30];
    float* outp = (float*)d_out;

    float* W = (float*)d_ws;
    size_t off = 0;
    auto alloc = [&](size_t n){ float* p = W + off; off += n; return p; };
    float* t1   = alloc((size_t)NB*NS*NDIN);
    float* t2   = alloc((size_t)NB*NS*NDIN);
    float* h1   = alloc((size_t)NB*NS*(2*NU));
    float* h2   = alloc((size_t)NB*NS*(2*NU));
    float* hT1  = alloc((size_t)NS*(2*NU)*NB);
    float* hT2  = alloc((size_t)NS*(2*NU)*NB);
    float* p1   = alloc((size_t)NB*NS*ND);
    float* p2   = alloc((size_t)NB*NS*ND);
    float* WTef = alloc((size_t)NH4*NU);
    float* WTeb = alloc((size_t)NH4*NU);
    float* WTdf = alloc((size_t)NH4*NU);
    float* WTdb = alloc((size_t)NH4*NU);
    float* hbfF = alloc((size_t)2*4*NU*NB/2 + 16);  // bf16 ping-pong + barrier ints
    float* vbuf = alloc((size_t)NB*NH8);
    float* preF = alloc((size_t)4*NS*NH4*NB/2);     // bf16: 4 x (NS*NH4*NB)
    ushort_t* hbf = (ushort_t*)hbfF;
    int* bar = (int*)(hbfF + (size_t)2*4*NU*NB/2);
    bf16* preb[4];
    for (int i = 0; i < 4; ++i) preb[i] = (bf16*)preF + (size_t)i*NS*NH4*NB;
    // fp32 aliases inside the (phase-idle) pre region:
    float* sim   = preF;
    float* simT  = preF + 1048576;
    float* P1    = preF + 2097152;
    float* P2    = preF + 3145728;
    float* beta  = preF + (size_t)NS*NH4*NB/2;
    float* alpha = preF + (size_t)2*NS*NH4*NB/2;

    // 1. zero tree buffers + barrier counters, fill leaves
    hipMemsetAsync(t1, 0, (size_t)2*NB*NS*NDIN*sizeof(float), stream);
    hipMemsetAsync(bar, 0, 2*sizeof(int), stream);
    k_embed<<<NB*NL, 128, 0, stream>>>(x1, char1, wemb, cemb, cfilt, t1);
    k_embed<<<NB*NL, 128, 0, stream>>>(x2, char2, wemb, cemb, cfilt, t2);
    k_tree<<<dim3(2, NB), 256, 0, stream>>>(temp1, len1, t1);
    k_tree<<<dim3(2, NB), 256, 0, stream>>>(temp2, len2, t2);

    // 2. weight transposes
    k_transp<<<dim3(38,10), dim3(32,8), 0, stream>>>(eWhf, WTef, NU, NH4);
    k_transp<<<dim3(38,10), dim3(32,8), 0, stream>>>(eWhb, WTeb, NU, NH4);
    k_transp<<<dim3(38,10), dim3(32,8), 0, stream>>>(dWhf, WTdf, NU, NH4);
    k_transp<<<dim3(38,10), dim3(32,8), 0, stream>>>(dWhb, WTdb, NU, NH4);

    // 3. encoder pre-activations (bf16, [t][col][b] layout)
    dim3 gpre(19, 128, 1);
    k_gemm_nn<1,1,0><<<gpre, 256, 0, stream>>>(t1, eWxf, ebf, preb[0], NB*NS, NH4, NDIN, 0,0,0);
    k_gemm_nn<1,1,0><<<gpre, 256, 0, stream>>>(t1, eWxb, ebb, preb[1], NB*NS, NH4, NDIN, 0,0,0);
    k_gemm_nn<1,1,0><<<gpre, 256, 0, stream>>>(t2, eWxf, ebf, preb[2], NB*NS, NH4, NDIN, 0,0,0);
    k_gemm_nn<1,1,0><<<gpre, 256, 0, stream>>>(t2, eWxb, ebb, preb[3], NB*NS, NH4, NDIN, 0,0,0);

    // 4. encoder LSTM (persistent, 1 launch)
    k_lstm_phase<<<300, 128, 0, stream>>>(preb[0], preb[1], preb[2], preb[3],
                                          WTef, WTeb, hT1, hT2, hbf, bar);
    k_transp<<<dim3(2,2400), dim3(32,8), 0, stream>>>(hT1, h1, NS*(2*NU), NB);
    k_transp<<<dim3(2,2400), dim3(32,8), 0, stream>>>(hT2, h2, NS*(2*NU), NB);

    // 5. attention
    k_gemm_nt_sim<<<dim3(2,2,NB), 256, 0, stream>>>(h1, h2, sim, simT);
    k_softmax<<<NB*NS, 128, 0, stream>>>(sim,  P1);
    k_softmax<<<NB*NS, 128, 0, stream>>>(simT, P2);
    k_gemm_nn<0,0,0><<<dim3(10,2,NB), 256, 0, stream>>>(P1, h2, nullptr, beta,  NS, 2*NU, NS,
                                                        (long long)NS*NS, (long long)NS*2*NU, (long long)NS*2*NU);
    k_gemm_nn<0,0,0><<<dim3(10,2,NB), 256, 0, stream>>>(P2, h1, nullptr, alpha, NS, 2*NU, NS,
                                                        (long long)NS*NS, (long long)NS*2*NU, (long long)NS*2*NU);

    // 6. m projection
    k_m_gemm<<<dim3(5,128), 256, 0, stream>>>(h1, beta,  decW, decb, p1);
    k_m_gemm<<<dim3(5,128), 256, 0, stream>>>(h2, alpha, decW, decb, p2);

    // 7. decoder pre-activations
    k_gemm_nn<1,1,0><<<gpre, 256, 0, stream>>>(p1, dWxf, dbf, preb[0], NB*NS, NH4, ND, 0,0,0);
    k_gemm_nn<1,1,0><<<gpre, 256, 0, stream>>>(p1, dWxb, dbb, preb[1], NB*NS, NH4, ND, 0,0,0);
    k_gemm_nn<1,1,0><<<gpre, 256, 0, stream>>>(p2, dWxf, dbf, preb[2], NB*NS, NH4, ND, 0,0,0);
    k_gemm_nn<1,1,0><<<gpre, 256, 0, stream>>>(p2, dWxb, dbb, preb[3], NB*NS, NH4, ND, 0,0,0);

    // 8. decoder LSTM (persistent, 1 launch)
    k_lstm_phase<<<300, 128, 0, stream>>>(preb[0], preb[1], preb[2], preb[3],
                                          WTdf, WTdb, hT1, hT2, hbf, bar + 1);

    // 9. pool + final MLP
    k_pool<<<150, 256, 0, stream>>>(hT1, vbuf, 0);
    k_pool<<<150, 256, 0, stream>>>(hT2, vbuf, 1200);
    k_final<<<NB, 320, 0, stream>>>(vbuf, aW1, ab1, aW2, ab2, outp);
}

// Round 3
// 6807.647 us; speedup vs baseline: 2.2852x; 2.2852x over previous
//
#include <hip/hip_runtime.h>
#include <hip/hip_bf16.h>

typedef __hip_bfloat16 bf16;
typedef unsigned int uint_t;
typedef unsigned short ushort_t;

constexpr int NB  = 64;    // batch
constexpr int NL  = 64;    // words per sentence
constexpr int NT  = 63;    // template steps
constexpr int NCL = 16;    // chars per word
constexpr int NS  = 128;   // 1 + NL + NT
constexpr int ND  = 300;   // embed dim / hidden U
constexpr int NU  = 300;
constexpr int NCE = 8;
constexpr int NCF = 100;
constexpr int NCW = 5;
constexpr int NDIN = 400;  // ND + NCF
constexpr int NH4 = 1200;
constexpr int NH8 = 2400;
constexpr int NCLS = 3;
constexpr int UPB = 8;     // units per LSTM block
constexpr int UBLK = 38;   // ceil(300/8) unit-blocks per scan

__device__ __forceinline__ float sigf(float x)  { return 1.0f/(1.0f + __expf(-x)); }
__device__ __forceinline__ float tanhf_(float x){ return 2.0f/(1.0f + __expf(-2.0f*x)) - 1.0f; }
__device__ __forceinline__ ushort_t f2bf(float f){ bf16 v = __float2bfloat16(f); return *(ushort_t*)&v; }

// ---------------- embedding + char CNN -> tree leaf rows ----------------
__global__ void k_embed(const int* __restrict__ x, const int* __restrict__ chars,
                        const float* __restrict__ wemb, const float* __restrict__ cemb,
                        const float* __restrict__ filt, float* __restrict__ tout)
{
    int bl = blockIdx.x;
    int b = bl / NL, l = bl - b*NL;
    __shared__ float e[NCL][NCE];
    __shared__ int wid;
    int tid = threadIdx.x;
    if (tid < NCL*NCE) {
        int ci = tid / NCE, cc = tid - (tid/NCE)*NCE;
        int ch = chars[bl*NCL + ci];
        e[ci][cc] = cemb[ch*NCE + cc];
    }
    if (tid == 0) wid = x[bl];
    __syncthreads();
    float* dst = tout + ((size_t)b*NS + 1 + l) * NDIN;
    if (tid < NCF) {
        float mx = -1e30f;
        for (int w = 0; w < NCL-NCW+1; ++w) {
            float acc = 0.f;
            #pragma unroll
            for (int k = 0; k < NCW; ++k)
                #pragma unroll
                for (int c = 0; c < NCE; ++c)
                    acc += e[w+k][c] * filt[(k*NCE+c)*NCF + tid];
            mx = fmaxf(mx, acc);
        }
        dst[ND + tid] = mx;
    }
    int w0 = wid;
    for (int i = tid; i < ND; i += blockDim.x)
        dst[i] = wemb[(size_t)w0*ND + i];
}

// ---------------- tree unfold ----------------
__global__ void k_tree(const int* __restrict__ temp, const int* __restrict__ len_,
                       float* __restrict__ tr)
{
    int half = blockIdx.x, b = blockIdx.y;
    int d0base = half*200;
    __shared__ float lds[65*200];
    int tid = threadIdx.x;
    float* base = tr + (size_t)b*NS*NDIN;
    for (int i = tid; i < 65*200; i += 256) {
        int r = i/200, d = i - r*200;
        lds[i] = base[r*NDIN + d0base + d];
    }
    __syncthreads();
    int ln = len_[b];
    for (int s = 1; s < NT; ++s) {
        int c0 = temp[(b*NT + s)*2 + 0];
        int c1 = temp[(b*NT + s)*2 + 1];
        int tgt = ln + 1 + s;
        if (tid < 200) {
            int d = tid;
            float p = 0.5f*(lds[c0*200 + d] + lds[c1*200 + d]);
            if (tgt <= NL) lds[tgt*200 + d] += p;
            else base[(size_t)tgt*NDIN + d0base + d] = p;
        }
    }
    __syncthreads();
    for (int i = tid; i < 65*200; i += 256) {
        int r = i/200, d = i - r*200;
        base[r*NDIN + d0base + d] = lds[i];
    }
}

// ---------------- generic transpose out[c][r] = in[r][c] ----------------
__global__ void k_transp(const float* __restrict__ in, float* __restrict__ out, int R, int C)
{
    __shared__ float tile[32][33];
    int c0 = blockIdx.x*32, r0 = blockIdx.y*32;
    for (int i = threadIdx.y; i < 32; i += 8) {
        int r = r0 + i, c = c0 + threadIdx.x;
        tile[i][threadIdx.x] = (r < R && c < C) ? in[(size_t)r*C + c] : 0.f;
    }
    __syncthreads();
    for (int i = threadIdx.y; i < 32; i += 8) {
        int c = c0 + i, r = r0 + threadIdx.x;
        if (c < C && r < R) out[(size_t)c*R + r] = tile[threadIdx.x][i];
    }
}

// ---------------- generic tiled GEMM  C = A@B (+bias)(relu) ----------------
template<int APERM, int OMODE, int ACT>
__global__ void k_gemm_nn(const float* __restrict__ A, const float* __restrict__ Bm,
                          const float* __restrict__ bias, void* __restrict__ Cv,
                          int M, int N, int K,
                          long long strideA, long long strideB, long long strideC)
{
    int bz = blockIdx.z;
    const float* Ab = A + (size_t)bz*strideA;
    const float* Bb = Bm + (size_t)bz*strideB;
    __shared__ float As[16][64];
    __shared__ float Bs[16][68];
    int n0 = blockIdx.x*64, m0 = blockIdx.y*64;
    int tid = threadIdx.x;
    int tm = tid/16, tn = tid - tm*16;
    float acc[4][4] = {};
    for (int k0 = 0; k0 < K; k0 += 16) {
        {
            int row = tid>>2, kq = tid&3;
            int m = m0 + row;
            int arow;
            if (APERM) { int tq = m>>6, bb = m&63; arow = bb*NS + tq; } else arow = m;
            const float* src = Ab + (size_t)arow*K + k0 + kq*4;
            float4 v;
            if (k0 + 16 <= K) v = *(const float4*)src;
            else {
                v.x = (k0+kq*4+0 < K)? src[0] : 0.f;
                v.y = (k0+kq*4+1 < K)? src[1] : 0.f;
                v.z = (k0+kq*4+2 < K)? src[2] : 0.f;
                v.w = (k0+kq*4+3 < K)? src[3] : 0.f;
            }
            As[kq*4+0][row]=v.x; As[kq*4+1][row]=v.y; As[kq*4+2][row]=v.z; As[kq*4+3][row]=v.w;
        }
        {
            int kk = tid>>4, nq = tid&15;
            int n = n0 + nq*4; int kg = k0 + kk;
            float4 v = {0,0,0,0};
            if (kg < K) {
                const float* src = Bb + (size_t)kg*N + n;
                if (n + 4 <= N) v = *(const float4*)src;
                else { if(n+0<N)v.x=src[0]; if(n+1<N)v.y=src[1]; if(n+2<N)v.z=src[2]; }
            }
            Bs[kk][nq*4+0]=v.x; Bs[kk][nq*4+1]=v.y; Bs[kk][nq*4+2]=v.z; Bs[kk][nq*4+3]=v.w;
        }
        __syncthreads();
        #pragma unroll
        for (int kk = 0; kk < 16; ++kk) {
            float4 a  = *(const float4*)&As[kk][tm*4];
            float4 bq = *(const float4*)&Bs[kk][tn*4];
            acc[0][0]+=a.x*bq.x; acc[0][1]+=a.x*bq.y; acc[0][2]+=a.x*bq.z; acc[0][3]+=a.x*bq.w;
            acc[1][0]+=a.y*bq.x; acc[1][1]+=a.y*bq.y; acc[1][2]+=a.y*bq.z; acc[1][3]+=a.y*bq.w;
            acc[2][0]+=a.z*bq.x; acc[2][1]+=a.z*bq.y; acc[2][2]+=a.z*bq.z; acc[2][3]+=a.z*bq.w;
            acc[3][0]+=a.w*bq.x; acc[3][1]+=a.w*bq.y; acc[3][2]+=a.w*bq.z; acc[3][3]+=a.w*bq.w;
        }
        __syncthreads();
    }
    #pragma unroll
    for (int i = 0; i < 4; ++i) {
        int m = m0 + tm*4 + i;
        #pragma unroll
        for (int j = 0; j < 4; ++j) {
            int n = n0 + tn*4 + j;
            if (n >= N) continue;
            float val = acc[i][j];
            if (bias) val += bias[n];
            if (ACT == 1) val = fmaxf(val, 0.f);
            if (OMODE == 0) {
                float* C = (float*)Cv + (size_t)bz*strideC;
                C[(size_t)m*N + n] = val;
            } else {
                int tq = m>>6, bb = m&63;
                ((bf16*)Cv)[((size_t)tq*NH4 + n)*NB + bb] = __float2bfloat16(val);
            }
        }
    }
}

// ---------------- batched sim = h1 @ h2^T ----------------
__global__ void k_gemm_nt_sim(const float* __restrict__ h1g, const float* __restrict__ h2g,
                              float* __restrict__ sim, float* __restrict__ simT)
{
    int bz = blockIdx.z;
    const float* Ab = h1g + (size_t)bz*NS*(2*NU);
    const float* Bb = h2g + (size_t)bz*NS*(2*NU);
    __shared__ float As[16][64];
    __shared__ float Bs[16][68];
    int n0 = blockIdx.x*64, m0 = blockIdx.y*64;
    int tid = threadIdx.x;
    int tm = tid/16, tn = tid - tm*16;
    float acc[4][4] = {};
    const int K = 2*NU;
    for (int k0 = 0; k0 < K; k0 += 16) {
        int row = tid>>2, kq = tid&3;
        bool full = (k0 + 16 <= K);
        {
            const float* src = Ab + (size_t)(m0+row)*K + k0 + kq*4;
            float4 v = {0,0,0,0};
            if (full) v = *(const float4*)src;
            else { if(k0+kq*4+0<K)v.x=src[0]; if(k0+kq*4+1<K)v.y=src[1];
                   if(k0+kq*4+2<K)v.z=src[2]; if(k0+kq*4+3<K)v.w=src[3]; }
            As[kq*4+0][row]=v.x; As[kq*4+1][row]=v.y; As[kq*4+2][row]=v.z; As[kq*4+3][row]=v.w;
        }
        {
            const float* src = Bb + (size_t)(n0+row)*K + k0 + kq*4;
            float4 v = {0,0,0,0};
            if (full) v = *(const float4*)src;
            else { if(k0+kq*4+0<K)v.x=src[0]; if(k0+kq*4+1<K)v.y=src[1];
                   if(k0+kq*4+2<K)v.z=src[2]; if(k0+kq*4+3<K)v.w=src[3]; }
            Bs[kq*4+0][row]=v.x; Bs[kq*4+1][row]=v.y; Bs[kq*4+2][row]=v.z; Bs[kq*4+3][row]=v.w;
        }
        __syncthreads();
        #pragma unroll
        for (int kk = 0; kk < 16; ++kk) {
            float4 a  = *(const float4*)&As[kk][tm*4];
            float4 bq = *(const float4*)&Bs[kk][tn*4];
            acc[0][0]+=a.x*bq.x; acc[0][1]+=a.x*bq.y; acc[0][2]+=a.x*bq.z; acc[0][3]+=a.x*bq.w;
            acc[1][0]+=a.y*bq.x; acc[1][1]+=a.y*bq.y; acc[1][2]+=a.y*bq.z; acc[1][3]+=a.y*bq.w;
            acc[2][0]+=a.z*bq.x; acc[2][1]+=a.z*bq.y; acc[2][2]+=a.z*bq.z; acc[2][3]+=a.z*bq.w;
            acc[3][0]+=a.w*bq.x; acc[3][1]+=a.w*bq.y; acc[3][2]+=a.w*bq.z; acc[3][3]+=a.w*bq.w;
        }
        __syncthreads();
    }
    #pragma unroll
    for (int i = 0; i < 4; ++i) {
        int m = m0 + tm*4 + i;
        #pragma unroll
        for (int j = 0; j < 4; ++j) {
            int n = n0 + tn*4 + j;
            float val = acc[i][j];
            sim [((size_t)bz*NS + m)*NS + n] = val;
            simT[((size_t)bz*NS + n)*NS + m] = val;
        }
    }
}

// ---------------- row softmax (rows of length NS=128) ----------------
__global__ void k_softmax(const float* __restrict__ in, float* __restrict__ out)
{
    int r = blockIdx.x, tid = threadIdx.x;
    float v = in[(size_t)r*NS + tid];
    float m = v;
    for (int o = 32; o > 0; o >>= 1) m = fmaxf(m, __shfl_down(m, o, 64));
    __shared__ float red[2];
    if ((tid & 63) == 0) red[tid>>6] = m;
    __syncthreads();
    m = fmaxf(red[0], red[1]);
    float e = __expf(v - m);
    float s = e;
    for (int o = 32; o > 0; o >>= 1) s += __shfl_down(s, o, 64);
    __shared__ float red2[2];
    if ((tid & 63) == 0) red2[tid>>6] = s;
    __syncthreads();
    s = red2[0] + red2[1];
    out[(size_t)r*NS + tid] = e / s;
}

// ---------------- p = relu([h, a, h*a, h-a] @ dec_W + dec_b) ----------------
__global__ void k_m_gemm(const float* __restrict__ Hp, const float* __restrict__ Ap,
                         const float* __restrict__ Wd, const float* __restrict__ bd,
                         float* __restrict__ P)
{
    __shared__ float As[16][64];
    __shared__ float Bs[16][68];
    const int N = ND, K = NH8;
    int n0 = blockIdx.x*64, m0 = blockIdx.y*64;
    int tid = threadIdx.x;
    int tm = tid/16, tn = tid - tm*16;
    float acc[4][4] = {};
    for (int k0 = 0; k0 < K; k0 += 16) {
        {
            int row = tid>>2, kq = tid&3;
            int m = m0 + row;
            const float* hrow = Hp + (size_t)m*(2*NU);
            const float* arow = Ap + (size_t)m*(2*NU);
            #pragma unroll
            for (int jj = 0; jj < 4; ++jj) {
                int k = k0 + kq*4 + jj;
                int sel = k / 600, kk2 = k - sel*600;
                float hv = hrow[kk2], av = arow[kk2];
                float val = (sel==0)? hv : (sel==1)? av : (sel==2)? hv*av : hv - av;
                As[kq*4+jj][row] = val;
            }
        }
        {
            int kk = tid>>4, nq = tid&15;
            int n = n0 + nq*4; int kg = k0 + kk;
            const float* src = Wd + (size_t)kg*N + n;
            float4 v = {0,0,0,0};
            if (n + 4 <= N) v = *(const float4*)src;
            else { if(n+0<N)v.x=src[0]; if(n+1<N)v.y=src[1]; if(n+2<N)v.z=src[2]; }
            Bs[kk][nq*4+0]=v.x; Bs[kk][nq*4+1]=v.y; Bs[kk][nq*4+2]=v.z; Bs[kk][nq*4+3]=v.w;
        }
        __syncthreads();
        #pragma unroll
        for (int kk = 0; kk < 16; ++kk) {
            float4 a  = *(const float4*)&As[kk][tm*4];
            float4 bq = *(const float4*)&Bs[kk][tn*4];
            acc[0][0]+=a.x*bq.x; acc[0][1]+=a.x*bq.y; acc[0][2]+=a.x*bq.z; acc[0][3]+=a.x*bq.w;
            acc[1][0]+=a.y*bq.x; acc[1][1]+=a.y*bq.y; acc[1][2]+=a.y*bq.z; acc[1][3]+=a.y*bq.w;
            acc[2][0]+=a.z*bq.x; acc[2][1]+=a.z*bq.y; acc[2][2]+=a.z*bq.z; acc[2][3]+=a.z*bq.w;
            acc[3][0]+=a.w*bq.x; acc[3][1]+=a.w*bq.y; acc[3][2]+=a.w*bq.z; acc[3][3]+=a.w*bq.w;
        }
        __syncthreads();
    }
    #pragma unroll
    for (int i = 0; i < 4; ++i) {
        int m = m0 + tm*4 + i;
        #pragma unroll
        for (int j = 0; j < 4; ++j) {
            int n = n0 + tn*4 + j;
            if (n >= N) continue;
            P[(size_t)m*N + n] = fmaxf(acc[i][j] + bd[n], 0.f);
        }
    }
}

// ---------------- one LSTM step, all 4 scans, one launch per step ----------------
// grid 152 = 4 scans x 38 unit-blocks; block 256 = 8 units x 32 batch-pairs.
// LDS: weights 8u x 4g x 300 fp32 (38.4 KB) + h_{t-1} bf16 300x64 (38.4 KB).
// Kernel boundary provides the cross-step sync; no fences/atomics needed.
__global__ __launch_bounds__(256) void k_lstm_step(
    const bf16* __restrict__ pre0, const bf16* __restrict__ pre1,
    const bf16* __restrict__ pre2, const bf16* __restrict__ pre3,
    const float* __restrict__ WTf, const float* __restrict__ WTb,
    float* __restrict__ hT1, float* __restrict__ hT2,
    ushort_t* __restrict__ hping,      // [2][4][300][64] bf16 ping-pong
    float* __restrict__ cst, int t)
{
    __shared__ float   ws[32*300];     // [u_local*4+g][k]
    __shared__ ushort_t hs[300*64];    // h_{t-1} bf16 [k][b]
    int blk = blockIdx.x;
    int scan = blk / UBLK, cb = blk - scan*UBLK;
    int u0 = cb*UPB;
    int tid = threadIdx.x;
    const bf16* pre = (scan==0)?pre0:(scan==1)?pre1:(scan==2)?pre2:pre3;
    const float* WT = (scan & 1)? WTb : WTf;
    float* hT = (scan < 2)? hT1 : hT2;
    int coff = (scan & 1)? NU : 0;
    int tt = (scan & 1)? (NS-1-t) : t;
    int ul = tid >> 5, bp = tid & 31, b0 = bp*2;
    int u = u0 + ul;
    bool live = (u < NU);

    float accg[4][2] = {{0,0},{0,0},{0,0},{0,0}};
    if (t > 0) {
        // stage weights: 32 rows x 300 floats, float4
        for (int i = tid; i < 32*75; i += 256) {
            int r = i / 75, q = i - r*75;
            int urow = u0 + (r >> 2), g = r & 3;
            if (urow < NU) {
                float4 v = *(const float4*)&WT[(size_t)(g*NU + urow)*NU + q*4];
                *(float4*)&ws[r*300 + q*4] = v;
            }
        }
        // stage h_{t-1}: 2400 uint4
        {
            const uint4* src = (const uint4*)(hping + ((size_t)((t+1)&1)*4 + scan)*NU*NB);
            uint4* dst = (uint4*)hs;
            for (int i = tid; i < NU*NB/8; i += 256) dst[i] = src[i];
        }
        __syncthreads();
        if (live) {
            const float* wp = ws + ul*4*300;
            for (int j = 0; j < 300; j += 4) {
                float4 w0 = *(const float4*)(wp + 0*300 + j);
                float4 w1 = *(const float4*)(wp + 1*300 + j);
                float4 w2 = *(const float4*)(wp + 2*300 + j);
                float4 w3 = *(const float4*)(wp + 3*300 + j);
                uint_t hv0 = *(const uint_t*)&hs[(j+0)*NB + b0];
                uint_t hv1 = *(const uint_t*)&hs[(j+1)*NB + b0];
                uint_t hv2 = *(const uint_t*)&hs[(j+2)*NB + b0];
                uint_t hv3 = *(const uint_t*)&hs[(j+3)*NB + b0];
                float x0l = __uint_as_float(hv0 << 16), x0h = __uint_as_float(hv0 & 0xffff0000u);
                float x1l = __uint_as_float(hv1 << 16), x1h = __uint_as_float(hv1 & 0xffff0000u);
                float x2l = __uint_as_float(hv2 << 16), x2h = __uint_as_float(hv2 & 0xffff0000u);
                float x3l = __uint_as_float(hv3 << 16), x3h = __uint_as_float(hv3 & 0xffff0000u);
                accg[0][0] += w0.x*x0l + w0.y*x1l + w0.z*x2l + w0.w*x3l;
                accg[0][1] += w0.x*x0h + w0.y*x1h + w0.z*x2h + w0.w*x3h;
                accg[1][0] += w1.x*x0l + w1.y*x1l + w1.z*x2l + w1.w*x3l;
                accg[1][1] += w1.x*x0h + w1.y*x1h + w1.z*x2h + w1.w*x3h;
                accg[2][0] += w2.x*x0l + w2.y*x1l + w2.z*x2l + w2.w*x3l;
                accg[2][1] += w2.x*x0h + w2.y*x1h + w2.z*x2h + w2.w*x3h;
                accg[3][0] += w3.x*x0l + w3.y*x1l + w3.z*x2l + w3.w*x3l;
                accg[3][1] += w3.x*x0h + w3.y*x1h + w3.z*x2h + w3.w*x3h;
            }
        }
    }
    if (!live) return;
    const bf16* pp = pre + (size_t)tt*NH4*NB;
    float* cp = cst + ((size_t)scan*NU + u)*NB;
    ushort_t* hw = hping + ((size_t)(t&1)*4 + scan)*NU*NB + u*NB;
    float2 cold = {0.f, 0.f};
    if (t > 0) cold = *(const float2*)&cp[b0];
    ushort_t hbits[2];
    float cnew[2];
    #pragma unroll
    for (int bb = 0; bb < 2; ++bb) {
        int b = b0 + bb;
        float iv = accg[0][bb] + __bfloat162float(pp[(0*NU+u)*NB + b]);
        float gv = accg[1][bb] + __bfloat162float(pp[(1*NU+u)*NB + b]);
        float fv = accg[2][bb] + __bfloat162float(pp[(2*NU+u)*NB + b]);
        float ov = accg[3][bb] + __bfloat162float(pp[(3*NU+u)*NB + b]);
        float co = bb ? cold.y : cold.x;
        float c = sigf(fv + 1.0f)*co + sigf(iv)*tanhf_(gv);
        float h = sigf(ov)*tanhf_(c);
        cnew[bb] = c;
        hbits[bb] = f2bf(h);
        hT[((size_t)tt*(2*NU) + coff + u)*NB + b] = h;
    }
    *(float2*)&cp[b0] = make_float2(cnew[0], cnew[1]);
    *(uint_t*)&hw[b0] = (uint_t)hbits[0] | ((uint_t)hbits[1] << 16);
}

// ---------------- pool: sum & max over t from hT layout (NS,600,NB) ----------------
__global__ void k_pool(const float* __restrict__ dT, float* __restrict__ v, int voff)
{
    int u = blockIdx.x*4 + (threadIdx.x >> 6);
    int b = threadIdx.x & 63;
    float s = 0.f, m = -1e30f;
    for (int t = 0; t < NS; ++t) {
        float x = dT[((size_t)t*(2*NU) + u)*NB + b];
        s += x; m = fmaxf(m, x);
    }
    v[(size_t)b*NH8 + voff + u]       = s;
    v[(size_t)b*NH8 + voff + 600 + u] = m;
}

// ---------------- final MLP ----------------
__global__ void k_final(const float* __restrict__ v, const float* __restrict__ W1,
                        const float* __restrict__ b1, const float* __restrict__ W2,
                        const float* __restrict__ b2, float* __restrict__ out)
{
    __shared__ float vl[NH8];
    __shared__ float yl[ND];
    int b = blockIdx.x, tid = threadIdx.x;
    for (int i = tid; i < NH8; i += 320) vl[i] = v[(size_t)b*NH8 + i];
    __syncthreads();
    if (tid < ND) {
        float acc = b1[tid];
        for (int k = 0; k < NH8; ++k) acc += vl[k]*W1[(size_t)k*ND + tid];
        yl[tid] = tanhf_(acc);
    }
    __syncthreads();
    if (tid < NCLS) {
        float acc = b2[tid];
        for (int u = 0; u < ND; ++u) acc += yl[u]*W2[u*NCLS + tid];
        out[b*NCLS + tid] = acc;
    }
}

extern "C" void kernel_launch(void* const* d_in, const int* in_sizes, int n_in,
                              void* d_out, int out_size, void* d_ws, size_t ws_size,
                              hipStream_t stream)
{
    const int*   x1     = (const int*)d_in[0];
    const int*   x2     = (const int*)d_in[1];
    const int*   char1  = (const int*)d_in[2];
    const int*   char2  = (const int*)d_in[3];
    const int*   temp1  = (const int*)d_in[6];
    const int*   temp2  = (const int*)d_in[7];
    const int*   len1   = (const int*)d_in[8];
    const int*   len2   = (const int*)d_in[9];
    const float* wemb   = (const float*)d_in[10];
    const float* cemb   = (const float*)d_in[11];
    const float* cfilt  = (const float*)d_in[12];
    const float* eWxf   = (const float*)d_in[13];
    const float* eWhf   = (const float*)d_in[14];
    const float* ebf    = (const float*)d_in[15];
    const float* eWxb   = (const float*)d_in[16];
    const float* eWhb   = (const float*)d_in[17];
    const float* ebb    = (const float*)d_in[18];
    const float* decW   = (const float*)d_in[19];
    const float* decb   = (const float*)d_in[20];
    const float* dWxf   = (const float*)d_in[21];
    const float* dWhf   = (const float*)d_in[22];
    const float* dbf    = (const float*)d_in[23];
    const float* dWxb   = (const float*)d_in[24];
    const float* dWhb   = (const float*)d_in[25];
    const float* dbb    = (const float*)d_in[26];
    const float* aW1    = (const float*)d_in[27];
    const float* ab1    = (const float*)d_in[28];
    const float* aW2    = (const float*)d_in[29];
    const float* ab2    = (const float*)d_in[30];
    float* outp = (float*)d_out;

    float* W = (float*)d_ws;
    size_t off = 0;
    auto alloc = [&](size_t n){ float* p = W + off; off += n; return p; };
    float* t1   = alloc((size_t)NB*NS*NDIN);
    float* t2   = alloc((size_t)NB*NS*NDIN);
    float* h1   = alloc((size_t)NB*NS*(2*NU));
    float* h2   = alloc((size_t)NB*NS*(2*NU));
    float* hT1  = alloc((size_t)NS*(2*NU)*NB);
    float* hT2  = alloc((size_t)NS*(2*NU)*NB);
    float* p1   = alloc((size_t)NB*NS*ND);
    float* p2   = alloc((size_t)NB*NS*ND);
    float* WTef = alloc((size_t)NH4*NU);
    float* WTeb = alloc((size_t)NH4*NU);
    float* WTdf = alloc((size_t)NH4*NU);
    float* WTdb = alloc((size_t)NH4*NU);
    float* hbfF = alloc((size_t)2*4*NU*NB/2);       // bf16 ping-pong
    float* cstb = alloc((size_t)4*NU*NB);
    float* vbuf = alloc((size_t)NB*NH8);
    float* preF = alloc((size_t)4*NS*NH4*NB/2);     // bf16: 4 x (NS*NH4*NB)
    ushort_t* hbf = (ushort_t*)hbfF;
    bf16* preb[4];
    for (int i = 0; i < 4; ++i) preb[i] = (bf16*)preF + (size_t)i*NS*NH4*NB;
    // fp32 aliases inside the (phase-idle) pre region:
    float* sim   = preF;
    float* simT  = preF + 1048576;
    float* P1    = preF + 2097152;
    float* P2    = preF + 3145728;
    float* beta  = preF + (size_t)NS*NH4*NB/2;
    float* alpha = preF + (size_t)2*NS*NH4*NB/2;

    // 1. zero tree buffers, fill leaves
    hipMemsetAsync(t1, 0, (size_t)2*NB*NS*NDIN*sizeof(float), stream);
    k_embed<<<NB*NL, 128, 0, stream>>>(x1, char1, wemb, cemb, cfilt, t1);
    k_embed<<<NB*NL, 128, 0, stream>>>(x2, char2, wemb, cemb, cfilt, t2);
    k_tree<<<dim3(2, NB), 256, 0, stream>>>(temp1, len1, t1);
    k_tree<<<dim3(2, NB), 256, 0, stream>>>(temp2, len2, t2);

    // 2. weight transposes
    k_transp<<<dim3(38,10), dim3(32,8), 0, stream>>>(eWhf, WTef, NU, NH4);
    k_transp<<<dim3(38,10), dim3(32,8), 0, stream>>>(eWhb, WTeb, NU, NH4);
    k_transp<<<dim3(38,10), dim3(32,8), 0, stream>>>(dWhf, WTdf, NU, NH4);
    k_transp<<<dim3(38,10), dim3(32,8), 0, stream>>>(dWhb, WTdb, NU, NH4);

    // 3. encoder pre-activations (bf16, [t][col][b] layout)
    dim3 gpre(19, 128, 1);
    k_gemm_nn<1,1,0><<<gpre, 256, 0, stream>>>(t1, eWxf, ebf, preb[0], NB*NS, NH4, NDIN, 0,0,0);
    k_gemm_nn<1,1,0><<<gpre, 256, 0, stream>>>(t1, eWxb, ebb, preb[1], NB*NS, NH4, NDIN, 0,0,0);
    k_gemm_nn<1,1,0><<<gpre, 256, 0, stream>>>(t2, eWxf, ebf, preb[2], NB*NS, NH4, NDIN, 0,0,0);
    k_gemm_nn<1,1,0><<<gpre, 256, 0, stream>>>(t2, eWxb, ebb, preb[3], NB*NS, NH4, NDIN, 0,0,0);

    // 4. encoder LSTM (per-step launch; kernel boundary = sync)
    for (int t = 0; t < NS; ++t)
        k_lstm_step<<<4*UBLK, 256, 0, stream>>>(preb[0], preb[1], preb[2], preb[3],
                                                WTef, WTeb, hT1, hT2, hbf, cstb, t);
    k_transp<<<dim3(2,2400), dim3(32,8), 0, stream>>>(hT1, h1, NS*(2*NU), NB);
    k_transp<<<dim3(2,2400), dim3(32,8), 0, stream>>>(hT2, h2, NS*(2*NU), NB);

    // 5. attention
    k_gemm_nt_sim<<<dim3(2,2,NB), 256, 0, stream>>>(h1, h2, sim, simT);
    k_softmax<<<NB*NS, 128, 0, stream>>>(sim,  P1);
    k_softmax<<<NB*NS, 128, 0, stream>>>(simT, P2);
    k_gemm_nn<0,0,0><<<dim3(10,2,NB), 256, 0, stream>>>(P1, h2, nullptr, beta,  NS, 2*NU, NS,
                                                        (long long)NS*NS, (long long)NS*2*NU, (long long)NS*2*NU);
    k_gemm_nn<0,0,0><<<dim3(10,2,NB), 256, 0, stream>>>(P2, h1, nullptr, alpha, NS, 2*NU, NS,
                                                        (long long)NS*NS, (long long)NS*2*NU, (long long)NS*2*NU);

    // 6. m projection
    k_m_gemm<<<dim3(5,128), 256, 0, stream>>>(h1, beta,  decW, decb, p1);
    k_m_gemm<<<dim3(5,128), 256, 0, stream>>>(h2, alpha, decW, decb, p2);

    // 7. decoder pre-activations
    k_gemm_nn<1,1,0><<<gpre, 256, 0, stream>>>(p1, dWxf, dbf, preb[0], NB*NS, NH4, ND, 0,0,0);
    k_gemm_nn<1,1,0><<<gpre, 256, 0, stream>>>(p1, dWxb, dbb, preb[1], NB*NS, NH4, ND, 0,0,0);
    k_gemm_nn<1,1,0><<<gpre, 256, 0, stream>>>(p2, dWxf, dbf, preb[2], NB*NS, NH4, ND, 0,0,0);
    k_gemm_nn<1,1,0><<<gpre, 256, 0, stream>>>(p2, dWxb, dbb, preb[3], NB*NS, NH4, ND, 0,0,0);

    // 8. decoder LSTM
    for (int t = 0; t < NS; ++t)
        k_lstm_step<<<4*UBLK, 256, 0, stream>>>(preb[0], preb[1], preb[2], preb[3],
                                                WTdf, WTdb, hT1, hT2, hbf, cstb, t);

    // 9. pool + final MLP
    k_pool<<<150, 256, 0, stream>>>(hT1, vbuf, 0);
    k_pool<<<150, 256, 0, stream>>>(hT2, vbuf, 1200);
    k_final<<<NB, 320, 0, stream>>>(vbuf, aW1, ab1, aW2, ab2, outp);
}

// Round 4
// 5543.909 us; speedup vs baseline: 2.8061x; 1.2280x over previous
//
#include <hip/hip_runtime.h>
#include <hip/hip_bf16.h>

typedef __hip_bfloat16 bf16;
typedef unsigned int uint_t;
typedef unsigned short ushort_t;
typedef __bf16 bf16x8 __attribute__((ext_vector_type(8)));
typedef float f32x4 __attribute__((ext_vector_type(4)));

constexpr int NB  = 64;    // batch
constexpr int NL  = 64;    // words per sentence
constexpr int NT  = 63;    // template steps
constexpr int NCL = 16;    // chars per word
constexpr int NS  = 128;   // 1 + NL + NT
constexpr int ND  = 300;   // embed dim / hidden U
constexpr int NU  = 300;
constexpr int NCE = 8;
constexpr int NCF = 100;
constexpr int NCW = 5;
constexpr int NDIN = 400;  // ND + NCF
constexpr int NH4 = 1200;
constexpr int NH8 = 2400;
constexpr int NCLS = 3;
constexpr int UPB = 8;     // units per LSTM block
constexpr int UBLK = 38;   // ceil(300/8) unit-blocks per scan

__device__ __forceinline__ float sigf(float x)  { return 1.0f/(1.0f + __expf(-x)); }
__device__ __forceinline__ float tanhf_(float x){ return 2.0f/(1.0f + __expf(-2.0f*x)) - 1.0f; }
__device__ __forceinline__ ushort_t f2bf(float f){ bf16 v = __float2bfloat16(f); return *(ushort_t*)&v; }
__device__ __forceinline__ uint_t pk2(float a, float b){ return (uint_t)f2bf(a) | ((uint_t)f2bf(b) << 16); }

// ---------------- embedding + char CNN -> tree leaf rows ----------------
__global__ void k_embed(const int* __restrict__ x, const int* __restrict__ chars,
                        const float* __restrict__ wemb, const float* __restrict__ cemb,
                        const float* __restrict__ filt, float* __restrict__ tout)
{
    int bl = blockIdx.x;
    int b = bl / NL, l = bl - b*NL;
    __shared__ float e[NCL][NCE];
    __shared__ int wid;
    int tid = threadIdx.x;
    if (tid < NCL*NCE) {
        int ci = tid / NCE, cc = tid - (tid/NCE)*NCE;
        int ch = chars[bl*NCL + ci];
        e[ci][cc] = cemb[ch*NCE + cc];
    }
    if (tid == 0) wid = x[bl];
    __syncthreads();
    float* dst = tout + ((size_t)b*NS + 1 + l) * NDIN;
    if (tid < NCF) {
        float mx = -1e30f;
        for (int w = 0; w < NCL-NCW+1; ++w) {
            float acc = 0.f;
            #pragma unroll
            for (int k = 0; k < NCW; ++k)
                #pragma unroll
                for (int c = 0; c < NCE; ++c)
                    acc += e[w+k][c] * filt[(k*NCE+c)*NCF + tid];
            mx = fmaxf(mx, acc);
        }
        dst[ND + tid] = mx;
    }
    int w0 = wid;
    for (int i = tid; i < ND; i += blockDim.x)
        dst[i] = wemb[(size_t)w0*ND + i];
}

// ---------------- tree unfold ----------------
__global__ void k_tree(const int* __restrict__ temp, const int* __restrict__ len_,
                       float* __restrict__ tr)
{
    int half = blockIdx.x, b = blockIdx.y;
    int d0base = half*200;
    __shared__ float lds[65*200];
    int tid = threadIdx.x;
    float* base = tr + (size_t)b*NS*NDIN;
    for (int i = tid; i < 65*200; i += 256) {
        int r = i/200, d = i - r*200;
        lds[i] = base[r*NDIN + d0base + d];
    }
    __syncthreads();
    int ln = len_[b];
    for (int s = 1; s < NT; ++s) {
        int c0 = temp[(b*NT + s)*2 + 0];
        int c1 = temp[(b*NT + s)*2 + 1];
        int tgt = ln + 1 + s;
        if (tid < 200) {
            int d = tid;
            float p = 0.5f*(lds[c0*200 + d] + lds[c1*200 + d]);
            if (tgt <= NL) lds[tgt*200 + d] += p;
            else base[(size_t)tgt*NDIN + d0base + d] = p;
        }
    }
    __syncthreads();
    for (int i = tid; i < 65*200; i += 256) {
        int r = i/200, d = i - r*200;
        base[r*NDIN + d0base + d] = lds[i];
    }
}

// ---------------- generic fp32 transpose out[c][r] = in[r][c] ----------------
__global__ void k_transp(const float* __restrict__ in, float* __restrict__ out, int R, int C)
{
    __shared__ float tile[32][33];
    int c0 = blockIdx.x*32, r0 = blockIdx.y*32;
    for (int i = threadIdx.y; i < 32; i += 8) {
        int r = r0 + i, c = c0 + threadIdx.x;
        tile[i][threadIdx.x] = (r < R && c < C) ? in[(size_t)r*C + c] : 0.f;
    }
    __syncthreads();
    for (int i = threadIdx.y; i < 32; i += 8) {
        int c = c0 + i, r = r0 + threadIdx.x;
        if (c < C && r < R) out[(size_t)c*R + r] = tile[threadIdx.x][i];
    }
}

// ---------------- weight transpose + fp32->bf16, zero-padded ----------------
// in: w [K][N] fp32 ; out: wt [Npad][Kpad] bf16, wt[n][k] = w[k][n]
__global__ void k_wtb(const float* __restrict__ w, ushort_t* __restrict__ wt,
                      int K, int N, int Kpad, int Npad)
{
    __shared__ float tile[32][33];
    int k0 = blockIdx.x*32, n0 = blockIdx.y*32;
    for (int i = threadIdx.y; i < 32; i += 8) {
        int k = k0 + i, n = n0 + threadIdx.x;
        tile[i][threadIdx.x] = (k < K && n < N) ? w[(size_t)k*N + n] : 0.f;
    }
    __syncthreads();
    for (int i = threadIdx.y; i < 32; i += 8) {
        int n = n0 + i, k = k0 + threadIdx.x;
        if (n < Npad && k < Kpad) wt[(size_t)n*Kpad + k] = f2bf(tile[threadIdx.x][i]);
    }
}

// ---------------- MFMA bf16 GEMM, 128x128 tile, BK=32 ----------------
// APERM: 1 -> logical m = t*64+b maps to A row (m&63)*NS + (m>>6)
// AFMT : 0 = A bf16 [M][Kpad]; 1 = A fp32 [M][Ksrc] (zero for k>=Ksrc);
//        2 = A = [h, a, h*a, h-a] from two fp32 [M][600] (Kpad=2400)
// OMODE: 0 = fp32 C[m*ldc+n] (+bias, ACT) ; 1 = bf16 scatter out[((t*NH4)+n)*NB+b] (+bias);
//        2 = bf16 linear [m][ldc], relu+bias, zero cols N..ldc
template<int APERM, int AFMT, int OMODE, int ACT>
__global__ __launch_bounds__(256) void k_gemm_mfma(
    const void* __restrict__ Aa, const void* __restrict__ Ab2,
    const ushort_t* __restrict__ BT, const float* __restrict__ bias,
    void* __restrict__ Cv, int N, int Kpad, int ldc, int Ksrc)
{
    __shared__ __align__(16) ushort_t lds[2*512*8];   // A chunks [512][8], B chunks [512][8]
    int tid = threadIdx.x;
    int wave = tid >> 6, lane = tid & 63;
    int quad = lane >> 4, lr = lane & 15;
    int wm = wave >> 1, wn = wave & 1;
    int m0 = blockIdx.y * 128, n0 = blockIdx.x * 128;
    f32x4 acc[4][4] = {};
    const int nK = Kpad >> 5;
    for (int ks = 0; ks < nK; ++ks) {
        int k0 = ks << 5;
        // ---- stage A (128 rows x 32 k), fragment-major w/ XOR swizzle ----
        #pragma unroll
        for (int i = 0; i < 2; ++i) {
            int c = tid + i*256;
            int mr = c >> 2, q = c & 3;
            int mg = m0 + mr;
            int arow = APERM ? ((mg & 63)*NS + (mg >> 6)) : mg;
            int kk = k0 + q*8;
            uint4 v;
            if (AFMT == 0) {
                v = *(const uint4*)&((const ushort_t*)Aa)[(size_t)arow*Kpad + kk];
            } else if (AFMT == 1) {
                if (kk < Ksrc) {
                    const float* src = (const float*)Aa + (size_t)arow*Ksrc + kk;
                    float4 v0 = *(const float4*)src;
                    float4 v1 = *(const float4*)(src + 4);
                    v.x = pk2(v0.x, v0.y); v.y = pk2(v0.z, v0.w);
                    v.z = pk2(v1.x, v1.y); v.w = pk2(v1.z, v1.w);
                } else { v.x = 0; v.y = 0; v.z = 0; v.w = 0; }
            } else {
                int sel = kk / 600, k2 = kk - sel*600;
                const float* hp = (const float*)Aa  + (size_t)arow*600 + k2;
                const float* ap = (const float*)Ab2 + (size_t)arow*600 + k2;
                float4 h0 = *(const float4*)hp, h1v = *(const float4*)(hp + 4);
                float4 a0 = *(const float4*)ap, a1v = *(const float4*)(ap + 4);
                float r0x,r0y,r0z,r0w,r1x,r1y,r1z,r1w;
                if (sel == 0)      { r0x=h0.x;r0y=h0.y;r0z=h0.z;r0w=h0.w; r1x=h1v.x;r1y=h1v.y;r1z=h1v.z;r1w=h1v.w; }
                else if (sel == 1) { r0x=a0.x;r0y=a0.y;r0z=a0.z;r0w=a0.w; r1x=a1v.x;r1y=a1v.y;r1z=a1v.z;r1w=a1v.w; }
                else if (sel == 2) { r0x=h0.x*a0.x;r0y=h0.y*a0.y;r0z=h0.z*a0.z;r0w=h0.w*a0.w;
                                     r1x=h1v.x*a1v.x;r1y=h1v.y*a1v.y;r1z=h1v.z*a1v.z;r1w=h1v.w*a1v.w; }
                else               { r0x=h0.x-a0.x;r0y=h0.y-a0.y;r0z=h0.z-a0.z;r0w=h0.w-a0.w;
                                     r1x=h1v.x-a1v.x;r1y=h1v.y-a1v.y;r1z=h1v.z-a1v.z;r1w=h1v.w-a1v.w; }
                v.x = pk2(r0x, r0y); v.y = pk2(r0z, r0w);
                v.z = pk2(r1x, r1y); v.w = pk2(r1z, r1w);
            }
            int mi = mr >> 4, r = mr & 15;
            int cd = (mi*4 + q)*16 + (r ^ (q*2));
            *(uint4*)&lds[cd*8] = v;
        }
        // ---- stage B from BT [Npad][Kpad] bf16 ----
        #pragma unroll
        for (int i = 0; i < 2; ++i) {
            int c = tid + i*256;
            int nr = c >> 2, q = c & 3;
            uint4 v = *(const uint4*)&BT[(size_t)(n0 + nr)*Kpad + k0 + q*8];
            int ni = nr >> 4, r = nr & 15;
            int cd = 512 + (ni*4 + q)*16 + (r ^ (q*2));
            *(uint4*)&lds[cd*8] = v;
        }
        __syncthreads();
        bf16x8 afr[4], bfr[4];
        #pragma unroll
        for (int mi = 0; mi < 4; ++mi) {
            int mi8 = wm*4 + mi;
            int cd = (mi8*4 + quad)*16 + (lr ^ (quad*2));
            afr[mi] = *(const bf16x8*)&lds[cd*8];
        }
        #pragma unroll
        for (int ni = 0; ni < 4; ++ni) {
            int ni8 = wn*4 + ni;
            int cd = 512 + (ni8*4 + quad)*16 + (lr ^ (quad*2));
            bfr[ni] = *(const bf16x8*)&lds[cd*8];
        }
        #pragma unroll
        for (int mi = 0; mi < 4; ++mi)
            #pragma unroll
            for (int ni = 0; ni < 4; ++ni)
                acc[mi][ni] = __builtin_amdgcn_mfma_f32_16x16x32_bf16(afr[mi], bfr[ni], acc[mi][ni], 0, 0, 0);
        __syncthreads();
    }
    // ---- epilogue ----
    #pragma unroll
    for (int mi = 0; mi < 4; ++mi) {
        int mbase = m0 + (wm*4 + mi)*16 + quad*4;
        #pragma unroll
        for (int ni = 0; ni < 4; ++ni) {
            int n = n0 + (wn*4 + ni)*16 + lr;
            if (OMODE == 0) {
                if (n < N) {
                    float bv = bias ? bias[n] : 0.f;
                    float* C = (float*)Cv;
                    #pragma unroll
                    for (int r2 = 0; r2 < 4; ++r2) {
                        float v = acc[mi][ni][r2] + bv;
                        if (ACT) v = fmaxf(v, 0.f);
                        C[(size_t)(mbase + r2)*ldc + n] = v;
                    }
                }
            } else if (OMODE == 1) {
                if (n < N) {
                    float bv = bias ? bias[n] : 0.f;
                    int t = mbase >> 6, b0 = mbase & 63;
                    uint2 o;
                    o.x = pk2(acc[mi][ni][0] + bv, acc[mi][ni][1] + bv);
                    o.y = pk2(acc[mi][ni][2] + bv, acc[mi][ni][3] + bv);
                    *(uint2*)&((ushort_t*)Cv)[((size_t)t*NH4 + n)*NB + b0] = o;
                }
            } else {
                if (n < ldc) {
                    float bv = (bias && n < N) ? bias[n] : 0.f;
                    ushort_t* C = (ushort_t*)Cv;
                    #pragma unroll
                    for (int r2 = 0; r2 < 4; ++r2) {
                        float v = acc[mi][ni][r2] + bv;
                        if (ACT) v = fmaxf(v, 0.f);
                        C[(size_t)(mbase + r2)*ldc + n] = (n < N) ? f2bf(v) : (ushort_t)0;
                    }
                }
            }
        }
    }
}

// ---------------- generic tiled SIMT GEMM (attention only now) ----------------
template<int APERM, int OMODE, int ACT>
__global__ void k_gemm_nn(const float* __restrict__ A, const float* __restrict__ Bm,
                          const float* __restrict__ bias, void* __restrict__ Cv,
                          int M, int N, int K,
                          long long strideA, long long strideB, long long strideC)
{
    int bz = blockIdx.z;
    const float* Ab = A + (size_t)bz*strideA;
    const float* Bb = Bm + (size_t)bz*strideB;
    __shared__ float As[16][64];
    __shared__ float Bs[16][68];
    int n0 = blockIdx.x*64, m0 = blockIdx.y*64;
    int tid = threadIdx.x;
    int tm = tid/16, tn = tid - tm*16;
    float acc[4][4] = {};
    for (int k0 = 0; k0 < K; k0 += 16) {
        {
            int row = tid>>2, kq = tid&3;
            int m = m0 + row;
            int arow;
            if (APERM) { int tq = m>>6, bb = m&63; arow = bb*NS + tq; } else arow = m;
            const float* src = Ab + (size_t)arow*K + k0 + kq*4;
            float4 v;
            if (k0 + 16 <= K) v = *(const float4*)src;
            else {
                v.x = (k0+kq*4+0 < K)? src[0] : 0.f;
                v.y = (k0+kq*4+1 < K)? src[1] : 0.f;
                v.z = (k0+kq*4+2 < K)? src[2] : 0.f;
                v.w = (k0+kq*4+3 < K)? src[3] : 0.f;
            }
            As[kq*4+0][row]=v.x; As[kq*4+1][row]=v.y; As[kq*4+2][row]=v.z; As[kq*4+3][row]=v.w;
        }
        {
            int kk = tid>>4, nq = tid&15;
            int n = n0 + nq*4; int kg = k0 + kk;
            float4 v = {0,0,0,0};
            if (kg < K) {
                const float* src = Bb + (size_t)kg*N + n;
                if (n + 4 <= N) v = *(const float4*)src;
                else { if(n+0<N)v.x=src[0]; if(n+1<N)v.y=src[1]; if(n+2<N)v.z=src[2]; }
            }
            Bs[kk][nq*4+0]=v.x; Bs[kk][nq*4+1]=v.y; Bs[kk][nq*4+2]=v.z; Bs[kk][nq*4+3]=v.w;
        }
        __syncthreads();
        #pragma unroll
        for (int kk = 0; kk < 16; ++kk) {
            float4 a  = *(const float4*)&As[kk][tm*4];
            float4 bq = *(const float4*)&Bs[kk][tn*4];
            acc[0][0]+=a.x*bq.x; acc[0][1]+=a.x*bq.y; acc[0][2]+=a.x*bq.z; acc[0][3]+=a.x*bq.w;
            acc[1][0]+=a.y*bq.x; acc[1][1]+=a.y*bq.y; acc[1][2]+=a.y*bq.z; acc[1][3]+=a.y*bq.w;
            acc[2][0]+=a.z*bq.x; acc[2][1]+=a.z*bq.y; acc[2][2]+=a.z*bq.z; acc[2][3]+=a.z*bq.w;
            acc[3][0]+=a.w*bq.x; acc[3][1]+=a.w*bq.y; acc[3][2]+=a.w*bq.z; acc[3][3]+=a.w*bq.w;
        }
        __syncthreads();
    }
    #pragma unroll
    for (int i = 0; i < 4; ++i) {
        int m = m0 + tm*4 + i;
        #pragma unroll
        for (int j = 0; j < 4; ++j) {
            int n = n0 + tn*4 + j;
            if (n >= N) continue;
            float val = acc[i][j];
            if (bias) val += bias[n];
            if (ACT == 1) val = fmaxf(val, 0.f);
            if (OMODE == 0) {
                float* C = (float*)Cv + (size_t)bz*strideC;
                C[(size_t)m*N + n] = val;
            } else {
                int tq = m>>6, bb = m&63;
                ((bf16*)Cv)[((size_t)tq*NH4 + n)*NB + bb] = __float2bfloat16(val);
            }
        }
    }
}

// ---------------- batched sim = h1 @ h2^T ----------------
__global__ void k_gemm_nt_sim(const float* __restrict__ h1g, const float* __restrict__ h2g,
                              float* __restrict__ sim, float* __restrict__ simT)
{
    int bz = blockIdx.z;
    const float* Ab = h1g + (size_t)bz*NS*(2*NU);
    const float* Bb = h2g + (size_t)bz*NS*(2*NU);
    __shared__ float As[16][64];
    __shared__ float Bs[16][68];
    int n0 = blockIdx.x*64, m0 = blockIdx.y*64;
    int tid = threadIdx.x;
    int tm = tid/16, tn = tid - tm*16;
    float acc[4][4] = {};
    const int K = 2*NU;
    for (int k0 = 0; k0 < K; k0 += 16) {
        int row = tid>>2, kq = tid&3;
        bool full = (k0 + 16 <= K);
        {
            const float* src = Ab + (size_t)(m0+row)*K + k0 + kq*4;
            float4 v = {0,0,0,0};
            if (full) v = *(const float4*)src;
            else { if(k0+kq*4+0<K)v.x=src[0]; if(k0+kq*4+1<K)v.y=src[1];
                   if(k0+kq*4+2<K)v.z=src[2]; if(k0+kq*4+3<K)v.w=src[3]; }
            As[kq*4+0][row]=v.x; As[kq*4+1][row]=v.y; As[kq*4+2][row]=v.z; As[kq*4+3][row]=v.w;
        }
        {
            const float* src = Bb + (size_t)(n0+row)*K + k0 + kq*4;
            float4 v = {0,0,0,0};
            if (full) v = *(const float4*)src;
            else { if(k0+kq*4+0<K)v.x=src[0]; if(k0+kq*4+1<K)v.y=src[1];
                   if(k0+kq*4+2<K)v.z=src[2]; if(k0+kq*4+3<K)v.w=src[3]; }
            Bs[kq*4+0][row]=v.x; Bs[kq*4+1][row]=v.y; Bs[kq*4+2][row]=v.z; Bs[kq*4+3][row]=v.w;
        }
        __syncthreads();
        #pragma unroll
        for (int kk = 0; kk < 16; ++kk) {
            float4 a  = *(const float4*)&As[kk][tm*4];
            float4 bq = *(const float4*)&Bs[kk][tn*4];
            acc[0][0]+=a.x*bq.x; acc[0][1]+=a.x*bq.y; acc[0][2]+=a.x*bq.z; acc[0][3]+=a.x*bq.w;
            acc[1][0]+=a.y*bq.x; acc[1][1]+=a.y*bq.y; acc[1][2]+=a.y*bq.z; acc[1][3]+=a.y*bq.w;
            acc[2][0]+=a.z*bq.x; acc[2][1]+=a.z*bq.y; acc[2][2]+=a.z*bq.z; acc[2][3]+=a.z*bq.w;
            acc[3][0]+=a.w*bq.x; acc[3][1]+=a.w*bq.y; acc[3][2]+=a.w*bq.z; acc[3][3]+=a.w*bq.w;
        }
        __syncthreads();
    }
    #pragma unroll
    for (int i = 0; i < 4; ++i) {
        int m = m0 + tm*4 + i;
        #pragma unroll
        for (int j = 0; j < 4; ++j) {
            int n = n0 + tn*4 + j;
            float val = acc[i][j];
            sim [((size_t)bz*NS + m)*NS + n] = val;
            simT[((size_t)bz*NS + n)*NS + m] = val;
        }
    }
}

// ---------------- row softmax (rows of length NS=128) ----------------
__global__ void k_softmax(const float* __restrict__ in, float* __restrict__ out)
{
    int r = blockIdx.x, tid = threadIdx.x;
    float v = in[(size_t)r*NS + tid];
    float m = v;
    for (int o = 32; o > 0; o >>= 1) m = fmaxf(m, __shfl_down(m, o, 64));
    __shared__ float red[2];
    if ((tid & 63) == 0) red[tid>>6] = m;
    __syncthreads();
    m = fmaxf(red[0], red[1]);
    float e = __expf(v - m);
    float s = e;
    for (int o = 32; o > 0; o >>= 1) s += __shfl_down(s, o, 64);
    __shared__ float red2[2];
    if ((tid & 63) == 0) red2[tid>>6] = s;
    __syncthreads();
    s = red2[0] + red2[1];
    out[(size_t)r*NS + tid] = e / s;
}

// ---------------- one LSTM step, all 4 scans, one launch per step ----------------
__global__ __launch_bounds__(256) void k_lstm_step(
    const bf16* __restrict__ pre0, const bf16* __restrict__ pre1,
    const bf16* __restrict__ pre2, const bf16* __restrict__ pre3,
    const float* __restrict__ WTf, const float* __restrict__ WTb,
    float* __restrict__ hT1, float* __restrict__ hT2,
    ushort_t* __restrict__ hping,      // [2][4][300][64] bf16 ping-pong
    float* __restrict__ cst, int t)
{
    __shared__ float   ws[32*300];     // [u_local*4+g][k]
    __shared__ ushort_t hs[300*64];    // h_{t-1} bf16 [k][b]
    int blk = blockIdx.x;
    int scan = blk / UBLK, cb = blk - scan*UBLK;
    int u0 = cb*UPB;
    int tid = threadIdx.x;
    const bf16* pre = (scan==0)?pre0:(scan==1)?pre1:(scan==2)?pre2:pre3;
    const float* WT = (scan & 1)? WTb : WTf;
    float* hT = (scan < 2)? hT1 : hT2;
    int coff = (scan & 1)? NU : 0;
    int tt = (scan & 1)? (NS-1-t) : t;
    int ul = tid >> 5, bp = tid & 31, b0 = bp*2;
    int u = u0 + ul;
    bool live = (u < NU);

    float accg[4][2] = {{0,0},{0,0},{0,0},{0,0}};
    if (t > 0) {
        for (int i = tid; i < 32*75; i += 256) {
            int r = i / 75, q = i - r*75;
            int urow = u0 + (r >> 2), g = r & 3;
            if (urow < NU) {
                float4 v = *(const float4*)&WT[(size_t)(g*NU + urow)*NU + q*4];
                *(float4*)&ws[r*300 + q*4] = v;
            }
        }
        {
            const uint4* src = (const uint4*)(hping + ((size_t)((t+1)&1)*4 + scan)*NU*NB);
            uint4* dst = (uint4*)hs;
            for (int i = tid; i < NU*NB/8; i += 256) dst[i] = src[i];
        }
        __syncthreads();
        if (live) {
            const float* wp = ws + ul*4*300;
            for (int j = 0; j < 300; j += 4) {
                float4 w0 = *(const float4*)(wp + 0*300 + j);
                float4 w1 = *(const float4*)(wp + 1*300 + j);
                float4 w2 = *(const float4*)(wp + 2*300 + j);
                float4 w3 = *(const float4*)(wp + 3*300 + j);
                uint_t hv0 = *(const uint_t*)&hs[(j+0)*NB + b0];
                uint_t hv1 = *(const uint_t*)&hs[(j+1)*NB + b0];
                uint_t hv2 = *(const uint_t*)&hs[(j+2)*NB + b0];
                uint_t hv3 = *(const uint_t*)&hs[(j+3)*NB + b0];
                float x0l = __uint_as_float(hv0 << 16), x0h = __uint_as_float(hv0 & 0xffff0000u);
                float x1l = __uint_as_float(hv1 << 16), x1h = __uint_as_float(hv1 & 0xffff0000u);
                float x2l = __uint_as_float(hv2 << 16), x2h = __uint_as_float(hv2 & 0xffff0000u);
                float x3l = __uint_as_float(hv3 << 16), x3h = __uint_as_float(hv3 & 0xffff0000u);
                accg[0][0] += w0.x*x0l + w0.y*x1l + w0.z*x2l + w0.w*x3l;
                accg[0][1] += w0.x*x0h + w0.y*x1h + w0.z*x2h + w0.w*x3h;
                accg[1][0] += w1.x*x0l + w1.y*x1l + w1.z*x2l + w1.w*x3l;
                accg[1][1] += w1.x*x0h + w1.y*x1h + w1.z*x2h + w1.w*x3h;
                accg[2][0] += w2.x*x0l + w2.y*x1l + w2.z*x2l + w2.w*x3l;
                accg[2][1] += w2.x*x0h + w2.y*x1h + w2.z*x2h + w2.w*x3h;
                accg[3][0] += w3.x*x0l + w3.y*x1l + w3.z*x2l + w3.w*x3l;
                accg[3][1] += w3.x*x0h + w3.y*x1h + w3.z*x2h + w3.w*x3h;
            }
        }
    }
    if (!live) return;
    const bf16* pp = pre + (size_t)tt*NH4*NB;
    float* cp = cst + ((size_t)scan*NU + u)*NB;
    ushort_t* hw = hping + ((size_t)(t&1)*4 + scan)*NU*NB + u*NB;
    float2 cold = {0.f, 0.f};
    if (t > 0) cold = *(const float2*)&cp[b0];
    ushort_t hbits[2];
    float cnew[2];
    #pragma unroll
    for (int bb = 0; bb < 2; ++bb) {
        int b = b0 + bb;
        float iv = accg[0][bb] + __bfloat162float(pp[(0*NU+u)*NB + b]);
        float gv = accg[1][bb] + __bfloat162float(pp[(1*NU+u)*NB + b]);
        float fv = accg[2][bb] + __bfloat162float(pp[(2*NU+u)*NB + b]);
        float ov = accg[3][bb] + __bfloat162float(pp[(3*NU+u)*NB + b]);
        float co = bb ? cold.y : cold.x;
        float c = sigf(fv + 1.0f)*co + sigf(iv)*tanhf_(gv);
        float h = sigf(ov)*tanhf_(c);
        cnew[bb] = c;
        hbits[bb] = f2bf(h);
        hT[((size_t)tt*(2*NU) + coff + u)*NB + b] = h;
    }
    *(float2*)&cp[b0] = make_float2(cnew[0], cnew[1]);
    *(uint_t*)&hw[b0] = (uint_t)hbits[0] | ((uint_t)hbits[1] << 16);
}

// ---------------- pool ----------------
__global__ void k_pool(const float* __restrict__ dT, float* __restrict__ v, int voff)
{
    int u = blockIdx.x*4 + (threadIdx.x >> 6);
    int b = threadIdx.x & 63;
    float s = 0.f, m = -1e30f;
    for (int t = 0; t < NS; ++t) {
        float x = dT[((size_t)t*(2*NU) + u)*NB + b];
        s += x; m = fmaxf(m, x);
    }
    v[(size_t)b*NH8 + voff + u]       = s;
    v[(size_t)b*NH8 + voff + 600 + u] = m;
}

// ---------------- final MLP ----------------
__global__ void k_final(const float* __restrict__ v, const float* __restrict__ W1,
                        const float* __restrict__ b1, const float* __restrict__ W2,
                        const float* __restrict__ b2, float* __restrict__ out)
{
    __shared__ float vl[NH8];
    __shared__ float yl[ND];
    int b = blockIdx.x, tid = threadIdx.x;
    for (int i = tid; i < NH8; i += 320) vl[i] = v[(size_t)b*NH8 + i];
    __syncthreads();
    if (tid < ND) {
        float acc = b1[tid];
        for (int k = 0; k < NH8; ++k) acc += vl[k]*W1[(size_t)k*ND + tid];
        yl[tid] = tanhf_(acc);
    }
    __syncthreads();
    if (tid < NCLS) {
        float acc = b2[tid];
        for (int u = 0; u < ND; ++u) acc += yl[u]*W2[u*NCLS + tid];
        out[b*NCLS + tid] = acc;
    }
}

extern "C" void kernel_launch(void* const* d_in, const int* in_sizes, int n_in,
                              void* d_out, int out_size, void* d_ws, size_t ws_size,
                              hipStream_t stream)
{
    const int*   x1     = (const int*)d_in[0];
    const int*   x2     = (const int*)d_in[1];
    const int*   char1  = (const int*)d_in[2];
    const int*   char2  = (const int*)d_in[3];
    const int*   temp1  = (const int*)d_in[6];
    const int*   temp2  = (const int*)d_in[7];
    const int*   len1   = (const int*)d_in[8];
    const int*   len2   = (const int*)d_in[9];
    const float* wemb   = (const float*)d_in[10];
    const float* cemb   = (const float*)d_in[11];
    const float* cfilt  = (const float*)d_in[12];
    const float* eWxf   = (const float*)d_in[13];
    const float* eWhf   = (const float*)d_in[14];
    const float* ebf    = (const float*)d_in[15];
    const float* eWxb   = (const float*)d_in[16];
    const float* eWhb   = (const float*)d_in[17];
    const float* ebb    = (const float*)d_in[18];
    const float* decW   = (const float*)d_in[19];
    const float* decb   = (const float*)d_in[20];
    const float* dWxf   = (const float*)d_in[21];
    const float* dWhf   = (const float*)d_in[22];
    const float* dbf    = (const float*)d_in[23];
    const float* dWxb   = (const float*)d_in[24];
    const float* dWhb   = (const float*)d_in[25];
    const float* dbb    = (const float*)d_in[26];
    const float* aW1    = (const float*)d_in[27];
    const float* ab1    = (const float*)d_in[28];
    const float* aW2    = (const float*)d_in[29];
    const float* ab2    = (const float*)d_in[30];
    float* outp = (float*)d_out;

    float* W = (float*)d_ws;
    size_t off = 0;
    auto alloc = [&](size_t n){ float* p = W + off; off += n; return p; };
    float* t1   = alloc((size_t)NB*NS*NDIN);
    float* t2   = alloc((size_t)NB*NS*NDIN);
    float* h1   = alloc((size_t)NB*NS*(2*NU));
    float* h2   = alloc((size_t)NB*NS*(2*NU));
    float* hT1  = alloc((size_t)NS*(2*NU)*NB);
    float* hT2  = alloc((size_t)NS*(2*NU)*NB);
    float* WTef = alloc((size_t)NH4*NU);
    float* WTeb = alloc((size_t)NH4*NU);
    float* WTdf = alloc((size_t)NH4*NU);
    float* WTdb = alloc((size_t)NH4*NU);
    float* hbfF = alloc((size_t)2*4*NU*NB/2);       // bf16 ping-pong
    float* cstb = alloc((size_t)4*NU*NB);
    float* vbuf = alloc((size_t)NB*NH8);
    float* eWTfF = alloc((size_t)1280*416/2);
    float* eWTbF = alloc((size_t)1280*416/2);
    float* dWTfF = alloc((size_t)1280*320/2);
    float* dWTbF = alloc((size_t)1280*320/2);
    float* decWTF= alloc((size_t)384*2400/2);
    float* p1bfF = alloc((size_t)8192*320/2);
    float* p2bfF = alloc((size_t)8192*320/2);
    float* preF  = alloc((size_t)4*NS*NH4*NB/2);    // bf16: 4 x (NS*NH4*NB)
    ushort_t* hbf   = (ushort_t*)hbfF;
    ushort_t* eWTf  = (ushort_t*)eWTfF;
    ushort_t* eWTb  = (ushort_t*)eWTbF;
    ushort_t* dWTf  = (ushort_t*)dWTfF;
    ushort_t* dWTb  = (ushort_t*)dWTbF;
    ushort_t* decWT = (ushort_t*)decWTF;
    ushort_t* p1bf  = (ushort_t*)p1bfF;
    ushort_t* p2bf  = (ushort_t*)p2bfF;
    bf16* preb[4];
    for (int i = 0; i < 4; ++i) preb[i] = (bf16*)preF + (size_t)i*NS*NH4*NB;
    // fp32 aliases inside the (phase-idle) pre region:
    float* sim   = preF;
    float* simT  = preF + 1048576;
    float* P1    = preF + 2097152;
    float* P2    = preF + 3145728;
    float* beta  = preF + (size_t)NS*NH4*NB/2;
    float* alpha = preF + (size_t)2*NS*NH4*NB/2;

    // 1. zero tree buffers, fill leaves
    hipMemsetAsync(t1, 0, (size_t)2*NB*NS*NDIN*sizeof(float), stream);
    k_embed<<<NB*NL, 128, 0, stream>>>(x1, char1, wemb, cemb, cfilt, t1);
    k_embed<<<NB*NL, 128, 0, stream>>>(x2, char2, wemb, cemb, cfilt, t2);
    k_tree<<<dim3(2, NB), 256, 0, stream>>>(temp1, len1, t1);
    k_tree<<<dim3(2, NB), 256, 0, stream>>>(temp2, len2, t2);

    // 2. weight prep: fp32 recurrent transposes + bf16 W^T for MFMA
    k_transp<<<dim3(38,10), dim3(32,8), 0, stream>>>(eWhf, WTef, NU, NH4);
    k_transp<<<dim3(38,10), dim3(32,8), 0, stream>>>(eWhb, WTeb, NU, NH4);
    k_transp<<<dim3(38,10), dim3(32,8), 0, stream>>>(dWhf, WTdf, NU, NH4);
    k_transp<<<dim3(38,10), dim3(32,8), 0, stream>>>(dWhb, WTdb, NU, NH4);
    k_wtb<<<dim3(13,40), dim3(32,8), 0, stream>>>(eWxf, eWTf, 400, 1200, 416, 1280);
    k_wtb<<<dim3(13,40), dim3(32,8), 0, stream>>>(eWxb, eWTb, 400, 1200, 416, 1280);
    k_wtb<<<dim3(10,40), dim3(32,8), 0, stream>>>(dWxf, dWTf, 300, 1200, 320, 1280);
    k_wtb<<<dim3(10,40), dim3(32,8), 0, stream>>>(dWxb, dWTb, 300, 1200, 320, 1280);
    k_wtb<<<dim3(75,12), dim3(32,8), 0, stream>>>(decW, decWT, 2400, 300, 2400, 384);

    // 3. encoder pre-activations (MFMA bf16, fp32 A converted in staging)
    k_gemm_mfma<1,1,1,0><<<dim3(10,64), 256, 0, stream>>>(t1, nullptr, eWTf, ebf, preb[0], 1200, 416, 0, 400);
    k_gemm_mfma<1,1,1,0><<<dim3(10,64), 256, 0, stream>>>(t1, nullptr, eWTb, ebb, preb[1], 1200, 416, 0, 400);
    k_gemm_mfma<1,1,1,0><<<dim3(10,64), 256, 0, stream>>>(t2, nullptr, eWTf, ebf, preb[2], 1200, 416, 0, 400);
    k_gemm_mfma<1,1,1,0><<<dim3(10,64), 256, 0, stream>>>(t2, nullptr, eWTb, ebb, preb[3], 1200, 416, 0, 400);

    // 4. encoder LSTM (per-step launch; kernel boundary = sync)
    for (int t = 0; t < NS; ++t)
        k_lstm_step<<<4*UBLK, 256, 0, stream>>>(preb[0], preb[1], preb[2], preb[3],
                                                WTef, WTeb, hT1, hT2, hbf, cstb, t);
    k_transp<<<dim3(2,2400), dim3(32,8), 0, stream>>>(hT1, h1, NS*(2*NU), NB);
    k_transp<<<dim3(2,2400), dim3(32,8), 0, stream>>>(hT2, h2, NS*(2*NU), NB);

    // 5. attention (SIMT fp32)
    k_gemm_nt_sim<<<dim3(2,2,NB), 256, 0, stream>>>(h1, h2, sim, simT);
    k_softmax<<<NB*NS, 128, 0, stream>>>(sim,  P1);
    k_softmax<<<NB*NS, 128, 0, stream>>>(simT, P2);
    k_gemm_nn<0,0,0><<<dim3(10,2,NB), 256, 0, stream>>>(P1, h2, nullptr, beta,  NS, 2*NU, NS,
                                                        (long long)NS*NS, (long long)NS*2*NU, (long long)NS*2*NU);
    k_gemm_nn<0,0,0><<<dim3(10,2,NB), 256, 0, stream>>>(P2, h1, nullptr, alpha, NS, 2*NU, NS,
                                                        (long long)NS*NS, (long long)NS*2*NU, (long long)NS*2*NU);

    // 6. m projection (MFMA, fused [h,a,h*a,h-a] staging, bf16 out [8192][320])
    k_gemm_mfma<0,2,2,1><<<dim3(3,64), 256, 0, stream>>>(h1, beta,  decWT, decb, p1bf, 300, 2400, 320, 600);
    k_gemm_mfma<0,2,2,1><<<dim3(3,64), 256, 0, stream>>>(h2, alpha, decWT, decb, p2bf, 300, 2400, 320, 600);

    // 7. decoder pre-activations (MFMA, bf16 A)
    k_gemm_mfma<1,0,1,0><<<dim3(10,64), 256, 0, stream>>>(p1bf, nullptr, dWTf, dbf, preb[0], 1200, 320, 0, 320);
    k_gemm_mfma<1,0,1,0><<<dim3(10,64), 256, 0, stream>>>(p1bf, nullptr, dWTb, dbb, preb[1], 1200, 320, 0, 320);
    k_gemm_mfma<1,0,1,0><<<dim3(10,64), 256, 0, stream>>>(p2bf, nullptr, dWTf, dbf, preb[2], 1200, 320, 0, 320);
    k_gemm_mfma<1,0,1,0><<<dim3(10,64), 256, 0, stream>>>(p2bf, nullptr, dWTb, dbb, preb[3], 1200, 320, 0, 320);

    // 8. decoder LSTM
    for (int t = 0; t < NS; ++t)
        k_lstm_step<<<4*UBLK, 256, 0, stream>>>(preb[0], preb[1], preb[2], preb[3],
                                                WTdf, WTdb, hT1, hT2, hbf, cstb, t);

    // 9. pool + final MLP
    k_pool<<<150, 256, 0, stream>>>(hT1, vbuf, 0);
    k_pool<<<150, 256, 0, stream>>>(hT2, vbuf, 1200);
    k_final<<<NB, 320, 0, stream>>>(vbuf, aW1, ab1, aW2, ab2, outp);
}